// Round 1
// baseline (561.142 us; speedup 1.0000x reference)
//
#include <hip/hip_runtime.h>
#include <math.h>

#define HID 128
#define NN 512
#define NNODE 1024
#define CUTR 10.0f

// ---- ws layout, float offsets
#define WS_A    0            // [1024][256] fp32  (A_i + bias + const-angular row)
#define WS_N1T  262144       // nw1^T fp32 [128][256]
#define WS_N2T  294912       // nw2^T fp32 [128][128]
#define WS_B12  393216       // [128] fp32  eb2 @ cw1
// ---- ws layout, ushort offsets
#define SBMT_OFF  786688                  // BmT bf16 [2][256][512]  (c-major, j inner)
#define SE2T_OFF  (SBMT_OFF + 262144)     // ew2^T bf16 [128][256]
#define SW12T_OFF (SE2T_OFF + 32768)      // (ew2@cw1)^T bf16 [128][256]
#define SW1G_OFF  (SW12T_OFF + 32768)     // W1g^T bf16 [256][16]

// ---- out layout (float offsets)
#define OUT_POS 131072
#define OUT_VEL 133120

typedef __attribute__((ext_vector_type(8)))  short short8;
typedef __attribute__((ext_vector_type(4)))  unsigned short ushort4v;
typedef __attribute__((ext_vector_type(8)))  __bf16 bf16x8;
typedef __attribute__((ext_vector_type(4)))  float floatx4;
typedef __attribute__((ext_vector_type(16))) float float16;

__device__ __forceinline__ float silu_f(float x) {
  return x * __builtin_amdgcn_rcpf(1.f + __expf(-x));
}
__device__ __forceinline__ short f2bf(float x) {
  return __builtin_bit_cast(short, (__bf16)x);   // native v_cvt (RNE)
}
__device__ __forceinline__ float bf2f(unsigned short u) {
  union { unsigned u; float f; } v; v.u = ((unsigned)u) << 16;
  return v.f;
}
__device__ __forceinline__ bf16x8 as_bf(short8 s) {
  return __builtin_bit_cast(bf16x8, s);
}

// ---------------------------------------------------------------- K01
// blocks [0,256): A (fp32) + BmT (bf16) for 4 nodes each — ew1 row loaded
// once per 4 nodes (4x less L2 traffic than 1-node blocks).
// blocks [256,721): weight prep — W12^T, ew2^T, W1g^T, B12, nw1^T, nw2^T.
__global__ __launch_bounds__(256)
void k01_prep(const float* __restrict__ h, const float* __restrict__ ew1,
              const float* __restrict__ eb1, const float* __restrict__ ew2,
              const float* __restrict__ cw1, const float* __restrict__ eb2,
              const float* __restrict__ nw1, const float* __restrict__ nw2,
              float* __restrict__ ws, unsigned short* __restrict__ wsU) {
  int blk = blockIdx.x;
  int t = threadIdx.x;
  if (blk < 256) {
    __shared__ float sh_h[4][HID];
    int base = blk * 4;
    for (int idx = t; idx < 4*HID; idx += 256)
      sh_h[idx >> 7][idx & 127] = h[base*HID + idx];
    __syncthreads();
    int c = t;
    float bias = eb1[c] + ew1[264*256 + c];
    float a0=bias, a1=bias, a2=bias, a3=bias;
    float b0=0.f, b1=0.f, b2=0.f, b3=0.f;
#pragma unroll 4
    for (int k = 0; k < HID; ++k) {
      float ea = ew1[k*256 + c];
      float eb = ew1[(128+k)*256 + c];
      float h0 = sh_h[0][k], h1 = sh_h[1][k], h2 = sh_h[2][k], h3 = sh_h[3][k];
      a0 += h0*ea; b0 += h0*eb;
      a1 += h1*ea; b1 += h1*eb;
      a2 += h2*ea; b2 += h2*eb;
      a3 += h3*ea; b3 += h3*eb;
    }
    float av[4] = {a0,a1,a2,a3};
    float bv[4] = {b0,b1,b2,b3};
#pragma unroll
    for (int n = 0; n < 4; ++n) {
      int node = base + n;
      ws[WS_A + node*256 + c] = av[n];
      int b = node >> 9, j = node & 511;
      wsU[SBMT_OFF + b*131072 + c*512 + j] = (unsigned short)f2bf(bv[n]);
    }
  } else {
    int idx = (blk - 256) * 256 + t;
    if (idx < 32768) {
      // W12T[d][cp] = sum_c ew2[cp][c] * cw1[c][d]
      int d = idx & 127, cp = idx >> 7;
      float s = 0.f;
#pragma unroll 4
      for (int c = 0; c < 128; ++c) s += ew2[cp*128 + c] * cw1[c*128 + d];
      wsU[SW12T_OFF + d*256 + cp] = (unsigned short)f2bf(s);
    } else if (idx < 65536) {
      int i2 = idx - 32768; int c = i2 >> 8, k = i2 & 255;
      wsU[SE2T_OFF + c*256 + k] = (unsigned short)f2bf(ew2[k*HID + c]);
    } else if (idx < 69632) {
      int i3 = idx - 65536; int c = i3 >> 4, f = i3 & 15;
      int row = (f < 8) ? (256 + f) : (257 + f);
      wsU[SW1G_OFF + c*16 + f] = (unsigned short)f2bf(ew1[row*256 + c]);
    } else if (idx < 69760) {
      int d = idx - 69632;
      float s = 0.f;
#pragma unroll 4
      for (int c = 0; c < 128; ++c) s += eb2[c] * cw1[c*128 + d];
      ws[WS_B12 + d] = s;
    } else if (idx < 102528) {
      int i4 = idx - 69760; int d = i4 >> 8, k = i4 & 255;
      ws[WS_N1T + d*256 + k] = nw1[k*HID + d];
    } else if (idx < 118912) {
      int i5 = idx - 102528; int d = i5 >> 7, k = i5 & 127;
      ws[WS_N2T + d*128 + k] = nw2[k*HID + d];
    }
  }
}

// ---------------------------------------------------------------- K3
// One block per (b,i); 8 waves (512 threads), 32 hidden cols per wave.
// OCCUPANCY RESTRUCTURE (this round): previous 4-wave config sat at
// ~220 unified regs -> 2 waves/SIMD, latency-bound (VALU 41%, MFMA 6%).
// Halving per-wave state (1 phase1 MFMA, 2x f32x4 GEMM accs via
// 16x16x32 tiles) targets <=128 unified regs -> 4 waves/SIMD.
// __launch_bounds__(512,4) enforces the budget: 2 blocks/CU.
__global__ __launch_bounds__(512, 4)
void k3_edge(const float* __restrict__ pos, const float* __restrict__ vel,
             const float* __restrict__ h,
             const float* __restrict__ cb1, const float* __restrict__ cw2,
             const float* __restrict__ cb2, const float* __restrict__ eb2,
             const float* __restrict__ nb1, const float* __restrict__ nb2,
             const float* __restrict__ lng, const float* __restrict__ lnb,
             float* __restrict__ ws, float* __restrict__ out) {
  const short* wsS = (const short*)ws;
  const unsigned short* wsU = (const unsigned short*)ws;
  __shared__ __align__(16) short shH[2][32*256];  // bf16, xor-swizzled, double-buffered
  __shared__ float shsum[256];
  __shared__ float shred[24];

  const int t = threadIdx.x;
  const int w = t >> 6, l = t & 63, lo = l & 31, hl = l >> 5, hl4 = hl * 4;
  const int node = blockIdx.x;
  const int b = node >> 9;
  const int bN = b * NN;

  const int colg = (w << 5) + lo;          // hidden col 0..255 (one per wave-lane)
  const int dcol = (w << 4) + (l & 15);    // coord-hidden col 0..127
  const int kq   = l >> 4;                 // 0..3 (k-quarter for 16x16x32 frags)

  const bf16x8 wg = as_bf(*(const short8*)(wsS + SW1G_OFF + colg*16 + hl*8));

  const float a0   = ws[WS_A + node*256 + colg];
  const float cb1v = cb1[dcol];
  const float c2v  = cw2[dcol];
  const float b12v = ws[WS_B12 + dcol];
  const float cb2c = cb2[0] * (1.f/128.f);
  const float pix  = pos[node*2], piy = pos[node*2+1];

  float hs0 = 0.f;               // hsum partial for col colg
  float cs = 0.f;                // sum_j cut_j (per-lane over own j's)
  float S = 0.f, SX = 0.f, SY = 0.f;
  float cutv, pjx, pjy;
  float cutv_n, pjx_n, pjy_n;

  auto phase1 = [&](int jbw, int bufsel) {
    const int jb = jbw & (NN - 1);
    const int jn = bN + jb + lo;
    pjx_n = pos[2*jn]; pjy_n = pos[2*jn+1];
    const float dx = pix - pjx_n, dy = piy - pjy_n;
    const float dd = sqrtf(dx*dx + dy*dy);
    cutv_n = (dd < CUTR) ? 0.5f*(__cosf((float)M_PI*(1.f/CUTR)*dd) + 1.f) : 0.f;
    if (jbw >= NN) cutv_n = 0.f;
    short8 gs;
    if (hl == 0) {
#pragma unroll
      for (int k = 0; k < 8; ++k) {
        float ctr = (CUTR * (float)k) / 7.0f;
        float tt = (dd - ctr) * 0.8f;
        gs[k] = f2bf(__expf(-tt*tt));
      }
    } else {
      float invd = __builtin_amdgcn_rcpf(dd + 1e-8f);
      float c1 = dx * invd, s1 = dy * invd;
      if (dd == 0.f) { c1 = 1.f; s1 = 0.f; }
      float c2 = c1*c1 - s1*s1, s2 = 2.f*s1*c1;
      float c3 = c2*c1 - s2*s1, s3 = s2*c1 + c2*s1;
      float c4 = c3*c1 - s3*s1, s4 = s3*c1 + c3*s1;
      gs[0]=f2bf(c1); gs[1]=f2bf(c2); gs[2]=f2bf(c3); gs[3]=f2bf(c4);
      gs[4]=f2bf(s1); gs[5]=f2bf(s2); gs[6]=f2bf(s3); gs[7]=f2bf(s4);
    }
    const bf16x8 gf = as_bf(gs);
    short* shb = &shH[bufsel][0];
    const unsigned short* bt = wsU + SBMT_OFF + b*131072 + colg*512 + jb + hl4;
    float16 ci;
#pragma unroll
    for (int g = 0; g < 4; ++g) {
      ushort4v v4 = *(const ushort4v*)(bt + 8*g);
      ci[4*g+0] = bf2f(v4[0]) + a0;
      ci[4*g+1] = bf2f(v4[1]) + a0;
      ci[4*g+2] = bf2f(v4[2]) + a0;
      ci[4*g+3] = bf2f(v4[3]) + a0;
    }
    ci = __builtin_amdgcn_mfma_f32_32x32x16_bf16(gf, wg, ci, 0, 0, 0);
    const int ck = colg >> 3;
    float hacc = 0.f;
#pragma unroll
    for (int r = 0; r < 16; ++r) {
      int row = (r&3) + 8*(r>>2) + hl4;
      float sv = silu_f(ci[r]);
      hacc += __shfl(cutv_n, row, 32) * sv;
      shb[row*256 + (((ck ^ row) & 31) << 3) + (colg & 7)] = f2bf(sv);
    }
    hs0 += hacc;
  };

  // prologue: chunk 0 -> buf 0
  phase1(0, 0);
  cutv = cutv_n; pjx = pjx_n; pjy = pjy_n;
  __syncthreads();

  const short* wpBase = wsS + SW12T_OFF + dcol*256 + kq*8;
  const int rowA = l & 15, rowB = 16 + (l & 15);

  for (int k = 0; k < 16; ++k) {
    cs += cutv;

    // ---- GEMM: H @ W12 (K=256). Two 16x16x32 tiles per wave:
    // tile A rows j=0..15, tile B rows j=16..31, cols d = 16w..16w+15.
    floatx4 accA = {0.f, 0.f, 0.f, 0.f};
    floatx4 accB = {0.f, 0.f, 0.f, 0.f};
    {
      const short* shb = &shH[k & 1][0];
#pragma unroll
      for (int s = 0; s < 8; ++s) {
        bf16x8 wv = as_bf(*(const short8*)(wpBase + 32*s));
        const int ck = 4*s + kq;
        bf16x8 aA = as_bf(*(const short8*)(shb + rowA*256 + (((ck ^ rowA) & 31) << 3)));
        bf16x8 aB = as_bf(*(const short8*)(shb + rowB*256 + (((ck ^ rowB) & 31) << 3)));
        accA = __builtin_amdgcn_mfma_f32_16x16x32_bf16(aA, wv, accA, 0, 0, 0);
        accB = __builtin_amdgcn_mfma_f32_16x16x32_bf16(aB, wv, accB, 0, 0, 0);
      }
    }

    // ---- phase1 for chunk k+1 -> other buffer (overlaps the GEMM)
    phase1((k + 1) * 32, (k + 1) & 1);

    // ---- epilogue: c1 = cut*(acc+B12)+cb1; p = silu(c1)*cw2 + cb2/128
    const int jr = kq << 2;
#pragma unroll
    for (int r = 0; r < 4; ++r) {
      {
        int j = jr + r;
        float cr = __shfl(cutv, j, 32);
        float p = silu_f(cr * (accA[r] + b12v) + cb1v) * c2v + cb2c;
        S += p;
        SX += p * __shfl(pjx, j, 32);
        SY += p * __shfl(pjy, j, 32);
      }
      {
        int j = 16 + jr + r;
        float cr = __shfl(cutv, j, 32);
        float p = silu_f(cr * (accB[r] + b12v) + cb1v) * c2v + cb2c;
        S += p;
        SX += p * __shfl(pjx, j, 32);
        SY += p * __shfl(pjy, j, 32);
      }
    }

    cutv = cutv_n; pjx = pjx_n; pjy = pjy_n;
    __syncthreads();   // buf(k+1) writes complete; buf(k) reads complete
  }

  // ---- hsum: merge hl halves, stage to LDS
  hs0 += __shfl_xor(hs0, 32);
  if (hl == 0) shsum[colg] = hs0;

  // ---- cutsum: butterfly within 32 (identical across halves/waves)
  float cutsum = cs;
#pragma unroll
  for (int m = 1; m < 32; m <<= 1) cutsum += __shfl_xor(cutsum, m, 32);

  // ---- S/SX/SY wave reduce
#pragma unroll
  for (int off = 32; off > 0; off >>= 1) {
    S  += __shfl_xor(S, off);
    SX += __shfl_xor(SX, off);
    SY += __shfl_xor(SY, off);
  }
  if (l == 0) { shred[w] = S; shred[8 + w] = SX; shred[16 + w] = SY; }
  __syncthreads();

  // ================= fused node tail (512 threads, 4-way k-split) =======
  float* shIn  = (float*)&shH[0][0];    // 256 floats
  float* shHid = shIn + 256;            // 128 floats
  float* pm    = (float*)&shH[1][0];    // 512 float partials
  const int d  = t & 127, q = t >> 7;   // q in 0..3

  // ---- msg GEMV partials: pm[t] = sum over quarter q of c' of hsum*ew2T
  {
    const short* er = wsS + SE2T_OFF + d*256 + q*64;
    const float* ss = shsum + q*64;
    float m = 0.f;
#pragma unroll 4
    for (int kk = 0; kk < 8; ++kk) {
      short8 v = *(const short8*)(er + kk*8);
      const float4 s0 = *(const float4*)(ss + kk*8);
      const float4 s1 = *(const float4*)(ss + kk*8 + 4);
      m += bf2f((unsigned short)v[0])*s0.x + bf2f((unsigned short)v[1])*s0.y
         + bf2f((unsigned short)v[2])*s0.z + bf2f((unsigned short)v[3])*s0.w
         + bf2f((unsigned short)v[4])*s1.x + bf2f((unsigned short)v[5])*s1.y
         + bf2f((unsigned short)v[6])*s1.z + bf2f((unsigned short)v[7])*s1.w;
    }
    pm[t] = m;
  }
  if (t == 0) {
    float St = 0.f, SXt = 0.f, SYt = 0.f;
#pragma unroll
    for (int i = 0; i < 8; ++i) { St += shred[i]; SXt += shred[8+i]; SYt += shred[16+i]; }
    float updx = pix*St - SXt, updy = piy*St - SYt;
    out[OUT_POS + node*2+0] = pix + updx;
    out[OUT_POS + node*2+1] = piy + updy;
    out[OUT_VEL + node*2+0] = vel[node*2+0] + 0.1f*updx;
    out[OUT_VEL + node*2+1] = vel[node*2+1] + 0.1f*updy;
  }
  __syncthreads();

  // ---- assemble node input: h | msg
  if (t < HID) {
    shIn[t]       = h[node*HID + t];
    shIn[HID + t] = pm[t] + pm[t + 128] + pm[t + 256] + pm[t + 384] + eb2[t] * cutsum;
  }
  __syncthreads();

  // ---- MLP layer 1: pm[t] = partial over quarter-k of shIn*nw1T
  {
    const float* wr = ws + WS_N1T + d*256 + q*64;
    const float* si = shIn + q*64;
    float s = 0.f;
#pragma unroll 4
    for (int kk = 0; kk < 16; ++kk) {
      float4 wv = *(const float4*)(wr + kk*4);
      float4 iv = *(const float4*)(si + kk*4);
      s += wv.x*iv.x + wv.y*iv.y + wv.z*iv.z + wv.w*iv.w;
    }
    pm[t] = s;
  }
  __syncthreads();
  if (t < HID) shHid[t] = silu_f(nb1[t] + pm[t] + pm[t + 128] + pm[t + 256] + pm[t + 384]);
  __syncthreads();

  // ---- MLP layer 2 partials
  {
    const float* wr = ws + WS_N2T + d*128 + q*32;
    const float* si = shHid + q*32;
    float s = 0.f;
#pragma unroll 4
    for (int kk = 0; kk < 8; ++kk) {
      float4 wv = *(const float4*)(wr + kk*4);
      float4 iv = *(const float4*)(si + kk*4);
      s += wv.x*iv.x + wv.y*iv.y + wv.z*iv.z + wv.w*iv.w;
    }
    __syncthreads();   // pm reads (shHid stage) complete before overwrite
    pm[t] = s;
  }
  __syncthreads();

  // ---- residual + LayerNorm (t < 128)
  float x = 0.f;
  if (t < HID) {
    x = shIn[t] + nb2[t] + pm[t] + pm[t + 128] + pm[t + 256] + pm[t + 384];
    float v1 = x, v2 = x*x;
#pragma unroll
    for (int off = 32; off > 0; off >>= 1) {
      v1 += __shfl_down(v1, off);
      v2 += __shfl_down(v2, off);
    }
    if (l == 0) { shred[w] = v1; shred[2 + w] = v2; }
  }
  __syncthreads();
  if (t < HID) {
    float mu  = (shred[0] + shred[1]) * (1.f/HID);
    float var = (shred[2] + shred[3]) * (1.f/HID) - mu*mu;
    float inv = 1.f / sqrtf(var + 1e-5f);
    out[node*HID + t] = (x - mu) * inv * lng[t] + lnb[t];
  }
}

// ---------------------------------------------------------------- launch
extern "C" void kernel_launch(void* const* d_in, const int* in_sizes, int n_in,
                              void* d_out, int out_size, void* d_ws, size_t ws_size,
                              hipStream_t stream) {
  (void)in_sizes; (void)n_in; (void)out_size; (void)ws_size;
  const float* h   = (const float*)d_in[0];
  const float* pos = (const float*)d_in[1];
  const float* vel = (const float*)d_in[2];
  const float* ew1 = (const float*)d_in[3];
  const float* eb1 = (const float*)d_in[4];
  const float* ew2 = (const float*)d_in[5];
  const float* eb2 = (const float*)d_in[6];
  const float* cw1 = (const float*)d_in[7];
  const float* cb1 = (const float*)d_in[8];
  const float* cw2 = (const float*)d_in[9];
  const float* cb2 = (const float*)d_in[10];
  const float* nw1 = (const float*)d_in[11];
  const float* nb1 = (const float*)d_in[12];
  const float* nw2 = (const float*)d_in[13];
  const float* nb2 = (const float*)d_in[14];
  const float* lng = (const float*)d_in[15];
  const float* lnb = (const float*)d_in[16];
  float* out = (float*)d_out;
  float* ws  = (float*)d_ws;
  unsigned short* wsU = (unsigned short*)d_ws;

  hipLaunchKernelGGL(k01_prep, dim3(721), dim3(256), 0, stream,
                     h, ew1, eb1, ew2, cw1, eb2, nw1, nw2, ws, wsU);
  hipLaunchKernelGGL(k3_edge, dim3(NNODE), dim3(512), 0, stream,
                     pos, vel, h, cb1, cw2, cb2, eb2,
                     nb1, nb2, lng, lnb, ws, out);
}

// Round 2
// 406.685 us; speedup vs baseline: 1.3798x; 1.3798x over previous
//
#include <hip/hip_runtime.h>
#include <math.h>

#define HID 128
#define NN 512
#define NNODE 1024
#define CUTR 10.0f

// ---- ws layout, float offsets
#define WS_A    0            // [1024][256] fp32  (A_i + bias + const-angular row)
#define WS_N1T  262144       // nw1^T fp32 [128][256]
#define WS_N2T  294912       // nw2^T fp32 [128][128]
#define WS_B12  393216       // [128] fp32  eb2 @ cw1
// ---- ws layout, ushort offsets
#define SBMT_OFF  786688                  // BmT bf16 [2][256][512]  (c-major, j inner)
#define SE2T_OFF  (SBMT_OFF + 262144)     // ew2^T bf16 [128][256]
#define SW12T_OFF (SE2T_OFF + 32768)      // (ew2@cw1)^T bf16 [128][256]
#define SW1G_OFF  (SW12T_OFF + 32768)     // W1g^T bf16 [256][16]

// ---- out layout (float offsets)
#define OUT_POS 131072
#define OUT_VEL 133120

typedef __attribute__((ext_vector_type(8)))  short short8;
typedef __attribute__((ext_vector_type(4)))  unsigned short ushort4v;
typedef __attribute__((ext_vector_type(8)))  __bf16 bf16x8;
typedef __attribute__((ext_vector_type(16))) float float16;

__device__ __forceinline__ float silu_f(float x) {
  return x * __builtin_amdgcn_rcpf(1.f + __expf(-x));
}
__device__ __forceinline__ short f2bf(float x) {
  return __builtin_bit_cast(short, (__bf16)x);   // native v_cvt (RNE)
}
__device__ __forceinline__ float bf2f(unsigned short u) {
  union { unsigned u; float f; } v; v.u = ((unsigned)u) << 16;
  return v.f;
}
__device__ __forceinline__ bf16x8 as_bf(short8 s) {
  return __builtin_bit_cast(bf16x8, s);
}
__device__ __forceinline__ float16 zero16() {
  float16 z;
#pragma unroll
  for (int r = 0; r < 16; ++r) z[r] = 0.f;
  return z;
}

// ---------------------------------------------------------------- K01
// blocks [0,256): A (fp32) + BmT (bf16) for 4 nodes each — ew1 row loaded
// once per 4 nodes (4x less L2 traffic than 1-node blocks).
// blocks [256,721): weight prep — W12^T, ew2^T, W1g^T, B12, nw1^T, nw2^T.
__global__ __launch_bounds__(256)
void k01_prep(const float* __restrict__ h, const float* __restrict__ ew1,
              const float* __restrict__ eb1, const float* __restrict__ ew2,
              const float* __restrict__ cw1, const float* __restrict__ eb2,
              const float* __restrict__ nw1, const float* __restrict__ nw2,
              float* __restrict__ ws, unsigned short* __restrict__ wsU) {
  int blk = blockIdx.x;
  int t = threadIdx.x;
  if (blk < 256) {
    __shared__ float sh_h[4][HID];
    int base = blk * 4;
    for (int idx = t; idx < 4*HID; idx += 256)
      sh_h[idx >> 7][idx & 127] = h[base*HID + idx];
    __syncthreads();
    int c = t;
    float bias = eb1[c] + ew1[264*256 + c];
    float a0=bias, a1=bias, a2=bias, a3=bias;
    float b0=0.f, b1=0.f, b2=0.f, b3=0.f;
#pragma unroll 4
    for (int k = 0; k < HID; ++k) {
      float ea = ew1[k*256 + c];
      float eb = ew1[(128+k)*256 + c];
      float h0 = sh_h[0][k], h1 = sh_h[1][k], h2 = sh_h[2][k], h3 = sh_h[3][k];
      a0 += h0*ea; b0 += h0*eb;
      a1 += h1*ea; b1 += h1*eb;
      a2 += h2*ea; b2 += h2*eb;
      a3 += h3*ea; b3 += h3*eb;
    }
    float av[4] = {a0,a1,a2,a3};
    float bv[4] = {b0,b1,b2,b3};
#pragma unroll
    for (int n = 0; n < 4; ++n) {
      int node = base + n;
      ws[WS_A + node*256 + c] = av[n];
      int b = node >> 9, j = node & 511;
      wsU[SBMT_OFF + b*131072 + c*512 + j] = (unsigned short)f2bf(bv[n]);
    }
  } else {
    int idx = (blk - 256) * 256 + t;
    if (idx < 32768) {
      // W12T[d][cp] = sum_c ew2[cp][c] * cw1[c][d]
      int d = idx & 127, cp = idx >> 7;
      float s = 0.f;
#pragma unroll 4
      for (int c = 0; c < 128; ++c) s += ew2[cp*128 + c] * cw1[c*128 + d];
      wsU[SW12T_OFF + d*256 + cp] = (unsigned short)f2bf(s);
    } else if (idx < 65536) {
      int i2 = idx - 32768; int c = i2 >> 8, k = i2 & 255;
      wsU[SE2T_OFF + c*256 + k] = (unsigned short)f2bf(ew2[k*HID + c]);
    } else if (idx < 69632) {
      int i3 = idx - 65536; int c = i3 >> 4, f = i3 & 15;
      int row = (f < 8) ? (256 + f) : (257 + f);
      wsU[SW1G_OFF + c*16 + f] = (unsigned short)f2bf(ew1[row*256 + c]);
    } else if (idx < 69760) {
      int d = idx - 69632;
      float s = 0.f;
#pragma unroll 4
      for (int c = 0; c < 128; ++c) s += eb2[c] * cw1[c*128 + d];
      ws[WS_B12 + d] = s;
    } else if (idx < 102528) {
      int i4 = idx - 69760; int d = i4 >> 8, k = i4 & 255;
      ws[WS_N1T + d*256 + k] = nw1[k*HID + d];
    } else if (idx < 118912) {
      int i5 = idx - 102528; int d = i5 >> 7, k = i5 & 127;
      ws[WS_N2T + d*128 + k] = nw2[k*HID + d];
    }
  }
}

// ---------------------------------------------------------------- K3
// One block per (b,i); 4 waves. Round-0 structure + register diet:
//  (a) phase1 MFMA accumulates INTO ci (no separate hp)  -16 peak regs
//  (b) phase1(k+1) issued BEFORE the GEMM so ci/bt lifetimes don't
//      overlap acc2                                       -16 peak regs
//  (c) __launch_bounds__(256,3): 170-unified-reg budget -> 3 blocks/CU.
// ROUND-1 LESSON: the 128-reg tier (4 waves/SIMD) forces massive scratch
// spill (FETCH 4MB->785MB). 170 is the highest reachable tier. If FETCH
// balloons again here, revert to launch_bounds(256) with no min-waves.
__global__ __launch_bounds__(256, 3)
void k3_edge(const float* __restrict__ pos, const float* __restrict__ vel,
             const float* __restrict__ h,
             const float* __restrict__ cb1, const float* __restrict__ cw2,
             const float* __restrict__ cb2, const float* __restrict__ eb2,
             const float* __restrict__ nb1, const float* __restrict__ nb2,
             const float* __restrict__ lng, const float* __restrict__ lnb,
             float* __restrict__ ws, float* __restrict__ out) {
  const short* wsS = (const short*)ws;
  const unsigned short* wsU = (const unsigned short*)ws;
  __shared__ __align__(16) short shH[2][32*256];  // bf16, xor-swizzled, double-buffered
  __shared__ float shsum[256];
  __shared__ float shred[12];

  const int t = threadIdx.x;
  const int w = t >> 6, l = t & 63, lo = l & 31, hl = l >> 5, hl4 = hl * 4;
  const int node = blockIdx.x;
  const int b = node >> 9;
  const int bN = b * NN;

  const bf16x8 wg0 = as_bf(*(const short8*)(wsS + SW1G_OFF + (64*w + lo)*16 + hl*8));
  const bf16x8 wg1 = as_bf(*(const short8*)(wsS + SW1G_OFF + (64*w + 32 + lo)*16 + hl*8));

  const float a0   = ws[WS_A + node*256 + 64*w + lo];
  const float a1   = ws[WS_A + node*256 + 64*w + 32 + lo];
  const float cb1v = cb1[32*w + lo];
  const float c2v  = cw2[32*w + lo];
  const float b12v = ws[WS_B12 + 32*w + lo];
  const float cb2c = cb2[0] * (1.f/128.f);
  const float pix  = pos[node*2], piy = pos[node*2+1];

  float hs0 = 0.f, hs1 = 0.f;    // hsum partials for cols 64w+lo, 64w+32+lo
  float cs = 0.f;                // sum_j cut_j (per-lane over own j's)
  float S = 0.f, SX = 0.f, SY = 0.f;
  float cutv, pjx, pjy;
  float cutv_n, pjx_n, pjy_n;

  auto phase1 = [&](int jbw, int bufsel) {
    const int jb = jbw & (NN - 1);
    const int jn = bN + jb + lo;
    pjx_n = pos[2*jn]; pjy_n = pos[2*jn+1];
    const float dx = pix - pjx_n, dy = piy - pjy_n;
    const float d = sqrtf(dx*dx + dy*dy);
    cutv_n = (d < CUTR) ? 0.5f*(__cosf((float)M_PI*(1.f/CUTR)*d) + 1.f) : 0.f;
    if (jbw >= NN) cutv_n = 0.f;
    short8 gs;
    if (hl == 0) {
#pragma unroll
      for (int k = 0; k < 8; ++k) {
        float ctr = (CUTR * (float)k) / 7.0f;
        float tt = (d - ctr) * 0.8f;
        gs[k] = f2bf(__expf(-tt*tt));
      }
    } else {
      float invd = __builtin_amdgcn_rcpf(d + 1e-8f);
      float c1 = dx * invd, s1 = dy * invd;
      if (d == 0.f) { c1 = 1.f; s1 = 0.f; }
      float c2 = c1*c1 - s1*s1, s2 = 2.f*s1*c1;
      float c3 = c2*c1 - s2*s1, s3 = s2*c1 + c2*s1;
      float c4 = c3*c1 - s3*s1, s4 = s3*c1 + c3*s1;
      gs[0]=f2bf(c1); gs[1]=f2bf(c2); gs[2]=f2bf(c3); gs[3]=f2bf(c4);
      gs[4]=f2bf(s1); gs[5]=f2bf(s2); gs[6]=f2bf(s3); gs[7]=f2bf(s4);
    }
    const bf16x8 gf = as_bf(gs);
    short* shb = &shH[bufsel][0];
#pragma unroll
    for (int ct = 0; ct < 2; ++ct) {
      const int colg = 64*w + 32*ct + lo;
      const float av = ct ? a1 : a0;
      const unsigned short* bt = wsU + SBMT_OFF + b*131072 + colg*512 + jb + hl4;
      float16 ci;
#pragma unroll
      for (int g = 0; g < 4; ++g) {
        ushort4v v4 = *(const ushort4v*)(bt + 8*g);
        ci[4*g+0] = bf2f(v4[0]) + av;
        ci[4*g+1] = bf2f(v4[1]) + av;
        ci[4*g+2] = bf2f(v4[2]) + av;
        ci[4*g+3] = bf2f(v4[3]) + av;
      }
      ci = __builtin_amdgcn_mfma_f32_32x32x16_bf16(gf, ct ? wg1 : wg0, ci, 0, 0, 0);
      const int ck = colg >> 3;
      float hacc = 0.f;
#pragma unroll
      for (int r = 0; r < 16; ++r) {
        int row = (r&3) + 8*(r>>2) + hl4;
        float sv = silu_f(ci[r]);
        hacc += __shfl(cutv_n, row, 32) * sv;
        shb[row*256 + (((ck ^ row) & 31) << 3) + (colg & 7)] = f2bf(sv);
      }
      if (ct) hs1 += hacc; else hs0 += hacc;
    }
  };

  // prologue: chunk 0 -> buf 0
  phase1(0, 0);
  cutv = cutv_n; pjx = pjx_n; pjy = pjy_n;
  __syncthreads();

  for (int k = 0; k < 16; ++k) {
    cs += cutv;

    // ---- phase1 for chunk k+1 -> other buffer (issued first: its ci /
    // bt-load lifetimes end before acc2 goes live)
    phase1((k + 1) * 32, (k + 1) & 1);

    // ---- GEMM: H @ W12 (K=256), weights streamed from L1/L2
    float16 acc2 = zero16();
    {
      const short* wp = wsS + SW12T_OFF + (32*w + lo)*256 + hl*8;
      const short* shb = &shH[k & 1][0];
#pragma unroll 4
      for (int s = 0; s < 16; ++s) {
        bf16x8 wv = as_bf(*(const short8*)(wp + 16*s));
        const int ck = 2*s + hl;
        bf16x8 af = as_bf(*(const short8*)(shb + lo*256 + (((ck ^ lo) & 31) << 3)));
        acc2 = __builtin_amdgcn_mfma_f32_32x32x16_bf16(af, wv, acc2, 0, 0, 0);
      }
    }

    // ---- epilogue: c1 = cut*(acc2+B12)+cb1; p = silu(c1)*cw2 + cb2/128
#pragma unroll
    for (int r = 0; r < 16; ++r) {
      int row = (r&3) + 8*(r>>2) + hl4;
      float cr = __shfl(cutv, row, 32);
      float p = silu_f(cr * (acc2[r] + b12v) + cb1v) * c2v + cb2c;
      S += p;
      SX += p * __shfl(pjx, row, 32);
      SY += p * __shfl(pjy, row, 32);
    }

    cutv = cutv_n; pjx = pjx_n; pjy = pjy_n;
    __syncthreads();   // buf(k+1) writes complete; buf(k) reads complete
  }

  // ---- hsum: merge hl halves, stage to LDS
  hs0 += __shfl_xor(hs0, 32);
  hs1 += __shfl_xor(hs1, 32);
  if (hl == 0) {
    shsum[64*w + lo] = hs0;
    shsum[64*w + 32 + lo] = hs1;
  }

  // ---- cutsum: butterfly within 32 (identical across halves/waves)
  float cutsum = cs;
#pragma unroll
  for (int m = 1; m < 32; m <<= 1) cutsum += __shfl_xor(cutsum, m, 32);

  // ---- S/SX/SY wave reduce
#pragma unroll
  for (int off = 32; off > 0; off >>= 1) {
    S  += __shfl_xor(S, off);
    SX += __shfl_xor(SX, off);
    SY += __shfl_xor(SY, off);
  }
  if (l == 0) { shred[w] = S; shred[4 + w] = SX; shred[8 + w] = SY; }
  __syncthreads();

  // ================= fused node tail (all 256 threads) =================
  float* shIn  = (float*)&shH[0][0];    // 256 floats
  float* shHid = shIn + 256;            // 128 floats
  float* pm    = (float*)&shH[1][0];    // 256 float partials
  const int d  = t & 127, half = t >> 7;

  // ---- msg GEMV partials: pm[t] = sum over half of c' of hsum*ew2T
  {
    const short* er = wsS + SE2T_OFF + d*256 + half*128;
    const float* ss = shsum + half*128;
    float m = 0.f;
#pragma unroll 4
    for (int kk = 0; kk < 16; ++kk) {
      short8 v = *(const short8*)(er + kk*8);
      const float4 s0 = *(const float4*)(ss + kk*8);
      const float4 s1 = *(const float4*)(ss + kk*8 + 4);
      m += bf2f((unsigned short)v[0])*s0.x + bf2f((unsigned short)v[1])*s0.y
         + bf2f((unsigned short)v[2])*s0.z + bf2f((unsigned short)v[3])*s0.w
         + bf2f((unsigned short)v[4])*s1.x + bf2f((unsigned short)v[5])*s1.y
         + bf2f((unsigned short)v[6])*s1.z + bf2f((unsigned short)v[7])*s1.w;
    }
    pm[t] = m;
  }
  if (t == 0) {
    float St  = shred[0] + shred[1] + shred[2]  + shred[3];
    float SXt = shred[4] + shred[5] + shred[6]  + shred[7];
    float SYt = shred[8] + shred[9] + shred[10] + shred[11];
    float updx = pix*St - SXt, updy = piy*St - SYt;
    out[OUT_POS + node*2+0] = pix + updx;
    out[OUT_POS + node*2+1] = piy + updy;
    out[OUT_VEL + node*2+0] = vel[node*2+0] + 0.1f*updx;
    out[OUT_VEL + node*2+1] = vel[node*2+1] + 0.1f*updy;
  }
  __syncthreads();

  // ---- assemble node input: h | msg
  if (t < HID) {
    shIn[t]       = h[node*HID + t];
    shIn[HID + t] = pm[t] + pm[t + 128] + eb2[t] * cutsum;
  }
  __syncthreads();

  // ---- MLP layer 1: pm[t] = sum over half-k of shIn*nw1T (float4 loads)
  {
    const float* wr = ws + WS_N1T + d*256 + half*128;
    const float* si = shIn + half*128;
    float s = 0.f;
#pragma unroll 4
    for (int kk = 0; kk < 32; ++kk) {
      float4 wv = *(const float4*)(wr + kk*4);
      float4 iv = *(const float4*)(si + kk*4);
      s += wv.x*iv.x + wv.y*iv.y + wv.z*iv.z + wv.w*iv.w;
    }
    __syncthreads();   // pm reuse: msg reads done
    pm[t] = s;
  }
  __syncthreads();
  if (t < HID) shHid[t] = silu_f(nb1[t] + pm[t] + pm[t + 128]);
  __syncthreads();

  // ---- MLP layer 2 partials
  {
    const float* wr = ws + WS_N2T + d*128 + half*64;
    const float* si = shHid + half*64;
    float s = 0.f;
#pragma unroll 4
    for (int kk = 0; kk < 16; ++kk) {
      float4 wv = *(const float4*)(wr + kk*4);
      float4 iv = *(const float4*)(si + kk*4);
      s += wv.x*iv.x + wv.y*iv.y + wv.z*iv.z + wv.w*iv.w;
    }
    pm[t] = s;
  }
  __syncthreads();

  // ---- residual + LayerNorm (t < 128)
  float x = 0.f;
  if (t < HID) {
    x = shIn[t] + nb2[t] + pm[t] + pm[t + 128];
    float v1 = x, v2 = x*x;
#pragma unroll
    for (int off = 32; off > 0; off >>= 1) {
      v1 += __shfl_down(v1, off);
      v2 += __shfl_down(v2, off);
    }
    if (l == 0) { shred[w] = v1; shred[2 + w] = v2; }
  }
  __syncthreads();
  if (t < HID) {
    float mu  = (shred[0] + shred[1]) * (1.f/HID);
    float var = (shred[2] + shred[3]) * (1.f/HID) - mu*mu;
    float inv = 1.f / sqrtf(var + 1e-5f);
    out[node*HID + t] = (x - mu) * inv * lng[t] + lnb[t];
  }
}

// ---------------------------------------------------------------- launch
extern "C" void kernel_launch(void* const* d_in, const int* in_sizes, int n_in,
                              void* d_out, int out_size, void* d_ws, size_t ws_size,
                              hipStream_t stream) {
  (void)in_sizes; (void)n_in; (void)out_size; (void)ws_size;
  const float* h   = (const float*)d_in[0];
  const float* pos = (const float*)d_in[1];
  const float* vel = (const float*)d_in[2];
  const float* ew1 = (const float*)d_in[3];
  const float* eb1 = (const float*)d_in[4];
  const float* ew2 = (const float*)d_in[5];
  const float* eb2 = (const float*)d_in[6];
  const float* cw1 = (const float*)d_in[7];
  const float* cb1 = (const float*)d_in[8];
  const float* cw2 = (const float*)d_in[9];
  const float* cb2 = (const float*)d_in[10];
  const float* nw1 = (const float*)d_in[11];
  const float* nb1 = (const float*)d_in[12];
  const float* nw2 = (const float*)d_in[13];
  const float* nb2 = (const float*)d_in[14];
  const float* lng = (const float*)d_in[15];
  const float* lnb = (const float*)d_in[16];
  float* out = (float*)d_out;
  float* ws  = (float*)d_ws;
  unsigned short* wsU = (unsigned short*)d_ws;

  hipLaunchKernelGGL(k01_prep, dim3(721), dim3(256), 0, stream,
                     h, ew1, eb1, ew2, cw1, eb2, nw1, nw2, ws, wsU);
  hipLaunchKernelGGL(k3_edge, dim3(NNODE), dim3(256), 0, stream,
                     pos, vel, h, cb1, cw2, cb2, eb2,
                     nb1, nb2, lng, lnb, ws, out);
}

// Round 3
// 276.261 us; speedup vs baseline: 2.0312x; 1.4721x over previous
//
#include <hip/hip_runtime.h>
#include <math.h>

#define HID 128
#define NN 512
#define NNODE 1024
#define CUTR 10.0f

// ---- ws layout, float offsets
#define WS_A    0            // [1024][256] fp32  (A_i + bias + const-angular row)
#define WS_N1T  262144       // nw1^T fp32 [128][256]
#define WS_N2T  294912       // nw2^T fp32 [128][128]
#define WS_B12  393216       // [128] fp32  eb2 @ cw1
// ---- ws layout, ushort offsets
// BmT fragment-order bf16: [b][chunk16][g4][(col,hl)512][e4]
//   value BmT[c][j] (j = chunk*32 + e + 8g + 4hl) at
//   SBMT_OFF + b*131072 + chunk*8192 + g*2048 + (c*2+hl)*4 + e
//   -> phase1's per-g ushort4v load is 64-lane contiguous (512B/instr).
#define SBMT_OFF  786688                  // 262144 ushorts
#define SE2T_OFF  (SBMT_OFF + 262144)     // ew2^T bf16 [128][256]
// W12T fragment-order bf16: [s16][d128][hl2][e8]
//   value W12T[d][cp] (cp = 16s + 8hl + e) at
//   SW12T_OFF + s*2048 + d*16 + hl*8 + e
//   -> GEMM's per-s short8 load is 64-lane contiguous (1KB/instr).
#define SW12T_OFF (SE2T_OFF + 32768)      // 32768 ushorts
#define SW1G_OFF  (SW12T_OFF + 32768)     // W1g^T bf16 [256][16]

// ---- out layout (float offsets)
#define OUT_POS 131072
#define OUT_VEL 133120

typedef __attribute__((ext_vector_type(8)))  short short8;
typedef __attribute__((ext_vector_type(4)))  unsigned short ushort4v;
typedef __attribute__((ext_vector_type(8)))  __bf16 bf16x8;
typedef __attribute__((ext_vector_type(16))) float float16;

__device__ __forceinline__ float silu_f(float x) {
  return x * __builtin_amdgcn_rcpf(1.f + __expf(-x));
}
__device__ __forceinline__ short f2bf(float x) {
  return __builtin_bit_cast(short, (__bf16)x);   // native v_cvt (RNE)
}
__device__ __forceinline__ float bf2f(unsigned short u) {
  union { unsigned u; float f; } v; v.u = ((unsigned)u) << 16;
  return v.f;
}
__device__ __forceinline__ bf16x8 as_bf(short8 s) {
  return __builtin_bit_cast(bf16x8, s);
}
__device__ __forceinline__ float16 zero16() {
  float16 z;
#pragma unroll
  for (int r = 0; r < 16; ++r) z[r] = 0.f;
  return z;
}

// ---------------------------------------------------------------- K01
// blocks [0,256): A (fp32) + BmT (bf16, fragment order) for 4 nodes each.
// blocks [256,721): weight prep — W12^T (fragment order), ew2^T, W1g^T,
// B12, nw1^T, nw2^T.
__global__ __launch_bounds__(256)
void k01_prep(const float* __restrict__ h, const float* __restrict__ ew1,
              const float* __restrict__ eb1, const float* __restrict__ ew2,
              const float* __restrict__ cw1, const float* __restrict__ eb2,
              const float* __restrict__ nw1, const float* __restrict__ nw2,
              float* __restrict__ ws, unsigned short* __restrict__ wsU) {
  int blk = blockIdx.x;
  int t = threadIdx.x;
  if (blk < 256) {
    __shared__ float sh_h[4][HID];
    int base = blk * 4;
    for (int idx = t; idx < 4*HID; idx += 256)
      sh_h[idx >> 7][idx & 127] = h[base*HID + idx];
    __syncthreads();
    int c = t;
    float bias = eb1[c] + ew1[264*256 + c];
    float a0=bias, a1=bias, a2=bias, a3=bias;
    float b0=0.f, b1=0.f, b2=0.f, b3=0.f;
#pragma unroll 4
    for (int k = 0; k < HID; ++k) {
      float ea = ew1[k*256 + c];
      float eb = ew1[(128+k)*256 + c];
      float h0 = sh_h[0][k], h1 = sh_h[1][k], h2 = sh_h[2][k], h3 = sh_h[3][k];
      a0 += h0*ea; b0 += h0*eb;
      a1 += h1*ea; b1 += h1*eb;
      a2 += h2*ea; b2 += h2*eb;
      a3 += h3*ea; b3 += h3*eb;
    }
    float av[4] = {a0,a1,a2,a3};
    float bv[4] = {b0,b1,b2,b3};
#pragma unroll
    for (int n = 0; n < 4; ++n) {
      int node = base + n;
      ws[WS_A + node*256 + c] = av[n];
      int b = node >> 9, j = node & 511;
      int chunk = j >> 5, jr = j & 31;
      int e = jr & 3, hlw = (jr >> 2) & 1, g = jr >> 3;
      wsU[SBMT_OFF + b*131072 + chunk*8192 + g*2048 + (c*2 + hlw)*4 + e] =
          (unsigned short)f2bf(bv[n]);
    }
  } else {
    int idx = (blk - 256) * 256 + t;
    if (idx < 32768) {
      // W12T[d][cp] = sum_c ew2[cp][c] * cw1[c][d], fragment-order store
      int d = idx & 127, cp = idx >> 7;
      float s = 0.f;
#pragma unroll 4
      for (int c = 0; c < 128; ++c) s += ew2[cp*128 + c] * cw1[c*128 + d];
      int sg = cp >> 4, hlw = (cp >> 3) & 1, e = cp & 7;
      wsU[SW12T_OFF + sg*2048 + d*16 + hlw*8 + e] = (unsigned short)f2bf(s);
    } else if (idx < 65536) {
      int i2 = idx - 32768; int c = i2 >> 8, k = i2 & 255;
      wsU[SE2T_OFF + c*256 + k] = (unsigned short)f2bf(ew2[k*HID + c]);
    } else if (idx < 69632) {
      int i3 = idx - 65536; int c = i3 >> 4, f = i3 & 15;
      int row = (f < 8) ? (256 + f) : (257 + f);
      wsU[SW1G_OFF + c*16 + f] = (unsigned short)f2bf(ew1[row*256 + c]);
    } else if (idx < 69760) {
      int d = idx - 69632;
      float s = 0.f;
#pragma unroll 4
      for (int c = 0; c < 128; ++c) s += eb2[c] * cw1[c*128 + d];
      ws[WS_B12 + d] = s;
    } else if (idx < 102528) {
      int i4 = idx - 69760; int d = i4 >> 8, k = i4 & 255;
      ws[WS_N1T + d*256 + k] = nw1[k*HID + d];
    } else if (idx < 118912) {
      int i5 = idx - 102528; int d = i5 >> 7, k = i5 & 127;
      ws[WS_N2T + d*128 + k] = nw2[k*HID + d];
    }
  }
}

// ---------------------------------------------------------------- K3
// One block per (b,i); 4 waves. Round-0 structure (284 us base).
// REGISTER LAW (r0/r1/r2): this config is the 2-waves/SIMD tier
// (~220 unified regs). launch_bounds(256,3) -> spills + no occupancy
// gain (r2: 340us); launch_bounds(512,4) -> catastrophic spill (r1).
// Do NOT re-attempt occupancy tiers; do NOT add per-thread state.
// THIS ROUND: both hot global streams (BmT, W12T) re-stored by k01 in
// MFMA-fragment order so every load instruction's 64 lanes are
// contiguous (4-8 cache lines/instr instead of 32-64) — attacks the
// L2/TA request-rate stall (90% stall cycles at round 0).
__global__ __launch_bounds__(256)
void k3_edge(const float* __restrict__ pos, const float* __restrict__ vel,
             const float* __restrict__ h,
             const float* __restrict__ cb1, const float* __restrict__ cw2,
             const float* __restrict__ cb2, const float* __restrict__ eb2,
             const float* __restrict__ nb1, const float* __restrict__ nb2,
             const float* __restrict__ lng, const float* __restrict__ lnb,
             float* __restrict__ ws, float* __restrict__ out) {
  const short* wsS = (const short*)ws;
  const unsigned short* wsU = (const unsigned short*)ws;
  __shared__ __align__(16) short shH[2][32*256];  // bf16, xor-swizzled, double-buffered
  __shared__ float shsum[256];
  __shared__ float shred[12];

  const int t = threadIdx.x;
  const int w = t >> 6, l = t & 63, lo = l & 31, hl = l >> 5, hl4 = hl * 4;
  const int node = blockIdx.x;
  const int b = node >> 9;
  const int bN = b * NN;

  const bf16x8 wg0 = as_bf(*(const short8*)(wsS + SW1G_OFF + (64*w + lo)*16 + hl*8));
  const bf16x8 wg1 = as_bf(*(const short8*)(wsS + SW1G_OFF + (64*w + 32 + lo)*16 + hl*8));

  const float a0   = ws[WS_A + node*256 + 64*w + lo];
  const float a1   = ws[WS_A + node*256 + 64*w + 32 + lo];
  const float cb1v = cb1[32*w + lo];
  const float c2v  = cw2[32*w + lo];
  const float b12v = ws[WS_B12 + 32*w + lo];
  const float cb2c = cb2[0] * (1.f/128.f);
  const float pix  = pos[node*2], piy = pos[node*2+1];

  float hs0 = 0.f, hs1 = 0.f;    // hsum partials for cols 64w+lo, 64w+32+lo
  float cs = 0.f;                // sum_j cut_j (per-lane over own j's)
  float S = 0.f, SX = 0.f, SY = 0.f;
  float cutv, pjx, pjy;
  float cutv_n, pjx_n, pjy_n;

  auto phase1 = [&](int jbw, int bufsel) {
    const int jb = jbw & (NN - 1);
    const int chunk = jb >> 5;
    const int jn = bN + jb + lo;
    pjx_n = pos[2*jn]; pjy_n = pos[2*jn+1];
    const float dx = pix - pjx_n, dy = piy - pjy_n;
    const float d = sqrtf(dx*dx + dy*dy);
    cutv_n = (d < CUTR) ? 0.5f*(__cosf((float)M_PI*(1.f/CUTR)*d) + 1.f) : 0.f;
    if (jbw >= NN) cutv_n = 0.f;
    short8 gs;
    if (hl == 0) {
#pragma unroll
      for (int k = 0; k < 8; ++k) {
        float ctr = (CUTR * (float)k) / 7.0f;
        float tt = (d - ctr) * 0.8f;
        gs[k] = f2bf(__expf(-tt*tt));
      }
    } else {
      float invd = __builtin_amdgcn_rcpf(d + 1e-8f);
      float c1 = dx * invd, s1 = dy * invd;
      if (d == 0.f) { c1 = 1.f; s1 = 0.f; }
      float c2 = c1*c1 - s1*s1, s2 = 2.f*s1*c1;
      float c3 = c2*c1 - s2*s1, s3 = s2*c1 + c2*s1;
      float c4 = c3*c1 - s3*s1, s4 = s3*c1 + c3*s1;
      gs[0]=f2bf(c1); gs[1]=f2bf(c2); gs[2]=f2bf(c3); gs[3]=f2bf(c4);
      gs[4]=f2bf(s1); gs[5]=f2bf(s2); gs[6]=f2bf(s3); gs[7]=f2bf(s4);
    }
    const bf16x8 gf = as_bf(gs);
    short* shb = &shH[bufsel][0];
#pragma unroll
    for (int ct = 0; ct < 2; ++ct) {
      const int colg = 64*w + 32*ct + lo;
      const float av = ct ? a1 : a0;
      // fragment-order BmT: per-g ushort4v is 64-lane contiguous
      const unsigned short* bt =
          wsU + SBMT_OFF + b*131072 + chunk*8192 + (colg*2 + hl)*4;
      float16 ci;
#pragma unroll
      for (int g = 0; g < 4; ++g) {
        ushort4v v4 = *(const ushort4v*)(bt + g*2048);
        ci[4*g+0] = bf2f(v4[0]) + av;
        ci[4*g+1] = bf2f(v4[1]) + av;
        ci[4*g+2] = bf2f(v4[2]) + av;
        ci[4*g+3] = bf2f(v4[3]) + av;
      }
      ci = __builtin_amdgcn_mfma_f32_32x32x16_bf16(gf, ct ? wg1 : wg0, ci, 0, 0, 0);
      const int ck = colg >> 3;
      float hacc = 0.f;
#pragma unroll
      for (int r = 0; r < 16; ++r) {
        int row = (r&3) + 8*(r>>2) + hl4;
        float sv = silu_f(ci[r]);
        hacc += __shfl(cutv_n, row, 32) * sv;
        shb[row*256 + (((ck ^ row) & 31) << 3) + (colg & 7)] = f2bf(sv);
      }
      if (ct) hs1 += hacc; else hs0 += hacc;
    }
  };

  // prologue: chunk 0 -> buf 0
  phase1(0, 0);
  cutv = cutv_n; pjx = pjx_n; pjy = pjy_n;
  __syncthreads();

  for (int k = 0; k < 16; ++k) {
    cs += cutv;

    // ---- GEMM: H @ W12 (K=256), fragment-order weights (coalesced)
    float16 acc2 = zero16();
    {
      const short* wp = wsS + SW12T_OFF + (32*w + lo)*16 + hl*8;
      const short* shb = &shH[k & 1][0];
#pragma unroll 4
      for (int s = 0; s < 16; ++s) {
        bf16x8 wv = as_bf(*(const short8*)(wp + s*2048));
        const int ck = 2*s + hl;
        bf16x8 af = as_bf(*(const short8*)(shb + lo*256 + (((ck ^ lo) & 31) << 3)));
        acc2 = __builtin_amdgcn_mfma_f32_32x32x16_bf16(af, wv, acc2, 0, 0, 0);
      }
    }

    // ---- phase1 for chunk k+1 -> other buffer (overlaps the GEMM)
    phase1((k + 1) * 32, (k + 1) & 1);

    // ---- epilogue: c1 = cut*(acc2+B12)+cb1; p = silu(c1)*cw2 + cb2/128
#pragma unroll
    for (int r = 0; r < 16; ++r) {
      int row = (r&3) + 8*(r>>2) + hl4;
      float cr = __shfl(cutv, row, 32);
      float p = silu_f(cr * (acc2[r] + b12v) + cb1v) * c2v + cb2c;
      S += p;
      SX += p * __shfl(pjx, row, 32);
      SY += p * __shfl(pjy, row, 32);
    }

    cutv = cutv_n; pjx = pjx_n; pjy = pjy_n;
    __syncthreads();   // buf(k+1) writes complete; buf(k) reads complete
  }

  // ---- hsum: merge hl halves, stage to LDS
  hs0 += __shfl_xor(hs0, 32);
  hs1 += __shfl_xor(hs1, 32);
  if (hl == 0) {
    shsum[64*w + lo] = hs0;
    shsum[64*w + 32 + lo] = hs1;
  }

  // ---- cutsum: butterfly within 32 (identical across halves/waves)
  float cutsum = cs;
#pragma unroll
  for (int m = 1; m < 32; m <<= 1) cutsum += __shfl_xor(cutsum, m, 32);

  // ---- S/SX/SY wave reduce
#pragma unroll
  for (int off = 32; off > 0; off >>= 1) {
    S  += __shfl_xor(S, off);
    SX += __shfl_xor(SX, off);
    SY += __shfl_xor(SY, off);
  }
  if (l == 0) { shred[w] = S; shred[4 + w] = SX; shred[8 + w] = SY; }
  __syncthreads();

  // ================= fused node tail (all 256 threads) =================
  float* shIn  = (float*)&shH[0][0];    // 256 floats
  float* shHid = shIn + 256;            // 128 floats
  float* pm    = (float*)&shH[1][0];    // 256 float partials
  const int d  = t & 127, half = t >> 7;

  // ---- msg GEMV partials: pm[t] = sum over half of c' of hsum*ew2T
  {
    const short* er = wsS + SE2T_OFF + d*256 + half*128;
    const float* ss = shsum + half*128;
    float m = 0.f;
#pragma unroll 4
    for (int kk = 0; kk < 16; ++kk) {
      short8 v = *(const short8*)(er + kk*8);
      const float4 s0 = *(const float4*)(ss + kk*8);
      const float4 s1 = *(const float4*)(ss + kk*8 + 4);
      m += bf2f((unsigned short)v[0])*s0.x + bf2f((unsigned short)v[1])*s0.y
         + bf2f((unsigned short)v[2])*s0.z + bf2f((unsigned short)v[3])*s0.w
         + bf2f((unsigned short)v[4])*s1.x + bf2f((unsigned short)v[5])*s1.y
         + bf2f((unsigned short)v[6])*s1.z + bf2f((unsigned short)v[7])*s1.w;
    }
    pm[t] = m;
  }
  if (t == 0) {
    float St  = shred[0] + shred[1] + shred[2]  + shred[3];
    float SXt = shred[4] + shred[5] + shred[6]  + shred[7];
    float SYt = shred[8] + shred[9] + shred[10] + shred[11];
    float updx = pix*St - SXt, updy = piy*St - SYt;
    out[OUT_POS + node*2+0] = pix + updx;
    out[OUT_POS + node*2+1] = piy + updy;
    out[OUT_VEL + node*2+0] = vel[node*2+0] + 0.1f*updx;
    out[OUT_VEL + node*2+1] = vel[node*2+1] + 0.1f*updy;
  }
  __syncthreads();

  // ---- assemble node input: h | msg
  if (t < HID) {
    shIn[t]       = h[node*HID + t];
    shIn[HID + t] = pm[t] + pm[t + 128] + eb2[t] * cutsum;
  }
  __syncthreads();

  // ---- MLP layer 1: pm[t] = sum over half-k of shIn*nw1T (float4 loads)
  {
    const float* wr = ws + WS_N1T + d*256 + half*128;
    const float* si = shIn + half*128;
    float s = 0.f;
#pragma unroll 4
    for (int kk = 0; kk < 32; ++kk) {
      float4 wv = *(const float4*)(wr + kk*4);
      float4 iv = *(const float4*)(si + kk*4);
      s += wv.x*iv.x + wv.y*iv.y + wv.z*iv.z + wv.w*iv.w;
    }
    __syncthreads();   // pm reuse: msg reads done
    pm[t] = s;
  }
  __syncthreads();
  if (t < HID) shHid[t] = silu_f(nb1[t] + pm[t] + pm[t + 128]);
  __syncthreads();

  // ---- MLP layer 2 partials
  {
    const float* wr = ws + WS_N2T + d*128 + half*64;
    const float* si = shHid + half*64;
    float s = 0.f;
#pragma unroll 4
    for (int kk = 0; kk < 16; ++kk) {
      float4 wv = *(const float4*)(wr + kk*4);
      float4 iv = *(const float4*)(si + kk*4);
      s += wv.x*iv.x + wv.y*iv.y + wv.z*iv.z + wv.w*iv.w;
    }
    pm[t] = s;
  }
  __syncthreads();

  // ---- residual + LayerNorm (t < 128)
  float x = 0.f;
  if (t < HID) {
    x = shIn[t] + nb2[t] + pm[t] + pm[t + 128];
    float v1 = x, v2 = x*x;
#pragma unroll
    for (int off = 32; off > 0; off >>= 1) {
      v1 += __shfl_down(v1, off);
      v2 += __shfl_down(v2, off);
    }
    if (l == 0) { shred[w] = v1; shred[2 + w] = v2; }
  }
  __syncthreads();
  if (t < HID) {
    float mu  = (shred[0] + shred[1]) * (1.f/HID);
    float var = (shred[2] + shred[3]) * (1.f/HID) - mu*mu;
    float inv = 1.f / sqrtf(var + 1e-5f);
    out[node*HID + t] = (x - mu) * inv * lng[t] + lnb[t];
  }
}

// ---------------------------------------------------------------- launch
extern "C" void kernel_launch(void* const* d_in, const int* in_sizes, int n_in,
                              void* d_out, int out_size, void* d_ws, size_t ws_size,
                              hipStream_t stream) {
  (void)in_sizes; (void)n_in; (void)out_size; (void)ws_size;
  const float* h   = (const float*)d_in[0];
  const float* pos = (const float*)d_in[1];
  const float* vel = (const float*)d_in[2];
  const float* ew1 = (const float*)d_in[3];
  const float* eb1 = (const float*)d_in[4];
  const float* ew2 = (const float*)d_in[5];
  const float* eb2 = (const float*)d_in[6];
  const float* cw1 = (const float*)d_in[7];
  const float* cb1 = (const float*)d_in[8];
  const float* cw2 = (const float*)d_in[9];
  const float* cb2 = (const float*)d_in[10];
  const float* nw1 = (const float*)d_in[11];
  const float* nb1 = (const float*)d_in[12];
  const float* nw2 = (const float*)d_in[13];
  const float* nb2 = (const float*)d_in[14];
  const float* lng = (const float*)d_in[15];
  const float* lnb = (const float*)d_in[16];
  float* out = (float*)d_out;
  float* ws  = (float*)d_ws;
  unsigned short* wsU = (unsigned short*)d_ws;

  hipLaunchKernelGGL(k01_prep, dim3(721), dim3(256), 0, stream,
                     h, ew1, eb1, ew2, cw1, eb2, nw1, nw2, ws, wsU);
  hipLaunchKernelGGL(k3_edge, dim3(NNODE), dim3(256), 0, stream,
                     pos, vel, h, cb1, cw2, cb2, eb2,
                     nb1, nb2, lng, lnb, ws, out);
}

// Round 4
// 267.718 us; speedup vs baseline: 2.0960x; 1.0319x over previous
//
#include <hip/hip_runtime.h>
#include <math.h>

#define HID 128
#define NN 512
#define NNODE 1024
#define CUTR 10.0f

// ---- ws layout, float offsets
#define WS_A    0            // [1024][256] fp32  (A_i + bias + const-angular row)
#define WS_N1T  262144       // nw1^T fp32 [128][256]
#define WS_N2T  294912       // nw2^T fp32 [128][128]
#define WS_B12  393216       // [128] fp32  eb2 @ cw1
// ---- ws layout, ushort offsets
// BmT fragment-order bf16: [b][chunk16][g4][(col,hl)512][e4]
//   value BmT[c][j] (j = chunk*32 + e + 8g + 4hl) at
//   SBMT_OFF + b*131072 + chunk*8192 + g*2048 + (c*2+hl)*4 + e
//   -> phase1's per-g ushort4v load is 64-lane contiguous (512B/instr).
#define SBMT_OFF  786688                  // 262144 ushorts
#define SE2T_OFF  (SBMT_OFF + 262144)     // ew2^T bf16 [128][256]
// W12T fragment-order bf16: [s16][d128][hl2][e8]
//   value W12T[d][cp] (cp = 16s + 8hl + e) at
//   SW12T_OFF + s*2048 + d*16 + hl*8 + e
//   -> GEMM's per-s short8 load is 64-lane contiguous (1KB/instr).
#define SW12T_OFF (SE2T_OFF + 32768)      // 32768 ushorts
#define SW1G_OFF  (SW12T_OFF + 32768)     // W1g^T bf16 [256][16]

// ---- out layout (float offsets)
#define OUT_POS 131072
#define OUT_VEL 133120

typedef __attribute__((ext_vector_type(8)))  short short8;
typedef __attribute__((ext_vector_type(4)))  unsigned short ushort4v;
typedef __attribute__((ext_vector_type(8)))  __bf16 bf16x8;
typedef __attribute__((ext_vector_type(16))) float float16;

__device__ __forceinline__ float silu_f(float x) {
  return x * __builtin_amdgcn_rcpf(1.f + __expf(-x));
}
__device__ __forceinline__ short f2bf(float x) {
  return __builtin_bit_cast(short, (__bf16)x);   // native v_cvt (RNE)
}
__device__ __forceinline__ float bf2f(unsigned short u) {
  union { unsigned u; float f; } v; v.u = ((unsigned)u) << 16;
  return v.f;
}
__device__ __forceinline__ bf16x8 as_bf(short8 s) {
  return __builtin_bit_cast(bf16x8, s);
}
__device__ __forceinline__ float16 zero16() {
  float16 z;
#pragma unroll
  for (int r = 0; r < 16; ++r) z[r] = 0.f;
  return z;
}

// ---------------------------------------------------------------- K01
// blocks [0,256): A (fp32) + BmT (bf16, fragment order) for 4 nodes each.
// blocks [256,721): weight prep — W12^T (fragment order), ew2^T, W1g^T,
// B12, nw1^T, nw2^T.
__global__ __launch_bounds__(256)
void k01_prep(const float* __restrict__ h, const float* __restrict__ ew1,
              const float* __restrict__ eb1, const float* __restrict__ ew2,
              const float* __restrict__ cw1, const float* __restrict__ eb2,
              const float* __restrict__ nw1, const float* __restrict__ nw2,
              float* __restrict__ ws, unsigned short* __restrict__ wsU) {
  int blk = blockIdx.x;
  int t = threadIdx.x;
  if (blk < 256) {
    __shared__ float sh_h[4][HID];
    int base = blk * 4;
    for (int idx = t; idx < 4*HID; idx += 256)
      sh_h[idx >> 7][idx & 127] = h[base*HID + idx];
    __syncthreads();
    int c = t;
    float bias = eb1[c] + ew1[264*256 + c];
    float a0=bias, a1=bias, a2=bias, a3=bias;
    float b0=0.f, b1=0.f, b2=0.f, b3=0.f;
#pragma unroll 4
    for (int k = 0; k < HID; ++k) {
      float ea = ew1[k*256 + c];
      float eb = ew1[(128+k)*256 + c];
      float h0 = sh_h[0][k], h1 = sh_h[1][k], h2 = sh_h[2][k], h3 = sh_h[3][k];
      a0 += h0*ea; b0 += h0*eb;
      a1 += h1*ea; b1 += h1*eb;
      a2 += h2*ea; b2 += h2*eb;
      a3 += h3*ea; b3 += h3*eb;
    }
    float av[4] = {a0,a1,a2,a3};
    float bv[4] = {b0,b1,b2,b3};
#pragma unroll
    for (int n = 0; n < 4; ++n) {
      int node = base + n;
      ws[WS_A + node*256 + c] = av[n];
      int b = node >> 9, j = node & 511;
      int chunk = j >> 5, jr = j & 31;
      int e = jr & 3, hlw = (jr >> 2) & 1, g = jr >> 3;
      wsU[SBMT_OFF + b*131072 + chunk*8192 + g*2048 + (c*2 + hlw)*4 + e] =
          (unsigned short)f2bf(bv[n]);
    }
  } else {
    int idx = (blk - 256) * 256 + t;
    if (idx < 32768) {
      // W12T[d][cp] = sum_c ew2[cp][c] * cw1[c][d], fragment-order store
      int d = idx & 127, cp = idx >> 7;
      float s = 0.f;
#pragma unroll 4
      for (int c = 0; c < 128; ++c) s += ew2[cp*128 + c] * cw1[c*128 + d];
      int sg = cp >> 4, hlw = (cp >> 3) & 1, e = cp & 7;
      wsU[SW12T_OFF + sg*2048 + d*16 + hlw*8 + e] = (unsigned short)f2bf(s);
    } else if (idx < 65536) {
      int i2 = idx - 32768; int c = i2 >> 8, k = i2 & 255;
      wsU[SE2T_OFF + c*256 + k] = (unsigned short)f2bf(ew2[k*HID + c]);
    } else if (idx < 69632) {
      int i3 = idx - 65536; int c = i3 >> 4, f = i3 & 15;
      int row = (f < 8) ? (256 + f) : (257 + f);
      wsU[SW1G_OFF + c*16 + f] = (unsigned short)f2bf(ew1[row*256 + c]);
    } else if (idx < 69760) {
      int d = idx - 69632;
      float s = 0.f;
#pragma unroll 4
      for (int c = 0; c < 128; ++c) s += eb2[c] * cw1[c*128 + d];
      ws[WS_B12 + d] = s;
    } else if (idx < 102528) {
      int i4 = idx - 69760; int d = i4 >> 8, k = i4 & 255;
      ws[WS_N1T + d*256 + k] = nw1[k*HID + d];
    } else if (idx < 118912) {
      int i5 = idx - 102528; int d = i5 >> 7, k = i5 & 127;
      ws[WS_N2T + d*128 + k] = nw2[k*HID + d];
    }
  }
}

// ---------------------------------------------------------------- K3
// One block per (b,i); 4 waves. Round-0 structure + coalesced streams
// (r3, 215us) + THIS ROUND: transposed coord-GEMM.
// REGISTER LAW (r0/r1/r2): ~220 unified regs -> 2 waves/SIMD tier.
// launch_bounds(256,3) -> spills w/o occupancy gain (r2); (512,4) ->
// catastrophic spill (r1). Do NOT re-attempt occupancy tiers.
// TRANSPOSED GEMM (this round): mfma(wv, af, acc2) — A/B fragments have
// identical lane layouts for 32x32x16, so swapping operands computes
// D[d][j] with the SAME loads. Now col=lane=j: cutv/pjx/pjy are
// lane-local in the epilogue (removes 48 ds_bpermute/iter, the dominant
// dependent-latency chain) and SX/SY fold to one fma per iter via
// psum*pjx. d-indexed constants (B12,cb1,cw2) come from a 128xfloat4
// LDS fold-table via broadcast ds_read_b128 (conflict-free).
__global__ __launch_bounds__(256)
void k3_edge(const float* __restrict__ pos, const float* __restrict__ vel,
             const float* __restrict__ h,
             const float* __restrict__ cb1, const float* __restrict__ cw2,
             const float* __restrict__ cb2, const float* __restrict__ eb2,
             const float* __restrict__ nb1, const float* __restrict__ nb2,
             const float* __restrict__ lng, const float* __restrict__ lnb,
             float* __restrict__ ws, float* __restrict__ out) {
  const short* wsS = (const short*)ws;
  const unsigned short* wsU = (const unsigned short*)ws;
  __shared__ __align__(16) short shH[2][32*256];  // bf16, xor-swizzled, double-buffered
  __shared__ float shsum[256];
  __shared__ float shred[12];
  __shared__ float4 shTbl[128];                   // {B12[d], cb1[d], cw2[d], 0}

  const int t = threadIdx.x;
  const int w = t >> 6, l = t & 63, lo = l & 31, hl = l >> 5, hl4 = hl * 4;
  const int node = blockIdx.x;
  const int b = node >> 9;
  const int bN = b * NN;

  const bf16x8 wg0 = as_bf(*(const short8*)(wsS + SW1G_OFF + (64*w + lo)*16 + hl*8));
  const bf16x8 wg1 = as_bf(*(const short8*)(wsS + SW1G_OFF + (64*w + 32 + lo)*16 + hl*8));

  const float a0   = ws[WS_A + node*256 + 64*w + lo];
  const float a1   = ws[WS_A + node*256 + 64*w + 32 + lo];
  const float cb2c = cb2[0] * (1.f/128.f);
  const float pix  = pos[node*2], piy = pos[node*2+1];

  // fold table: one row per coord-hidden d
  if (t < 128) shTbl[t] = make_float4(ws[WS_B12 + t], cb1[t], cw2[t], 0.f);

  float hs0 = 0.f, hs1 = 0.f;    // hsum partials for cols 64w+lo, 64w+32+lo
  float cs = 0.f;                // sum_j cut_j (per-lane over own j's)
  float S = 0.f, SX = 0.f, SY = 0.f;
  float cutv, pjx, pjy;
  float cutv_n, pjx_n, pjy_n;

  auto phase1 = [&](int jbw, int bufsel) {
    const int jb = jbw & (NN - 1);
    const int chunk = jb >> 5;
    const int jn = bN + jb + lo;
    pjx_n = pos[2*jn]; pjy_n = pos[2*jn+1];
    const float dx = pix - pjx_n, dy = piy - pjy_n;
    const float d = sqrtf(dx*dx + dy*dy);
    cutv_n = (d < CUTR) ? 0.5f*(__cosf((float)M_PI*(1.f/CUTR)*d) + 1.f) : 0.f;
    if (jbw >= NN) cutv_n = 0.f;
    short8 gs;
    if (hl == 0) {
#pragma unroll
      for (int k = 0; k < 8; ++k) {
        float ctr = (CUTR * (float)k) / 7.0f;
        float tt = (d - ctr) * 0.8f;
        gs[k] = f2bf(__expf(-tt*tt));
      }
    } else {
      float invd = __builtin_amdgcn_rcpf(d + 1e-8f);
      float c1 = dx * invd, s1 = dy * invd;
      if (d == 0.f) { c1 = 1.f; s1 = 0.f; }
      float c2 = c1*c1 - s1*s1, s2 = 2.f*s1*c1;
      float c3 = c2*c1 - s2*s1, s3 = s2*c1 + c2*s1;
      float c4 = c3*c1 - s3*s1, s4 = s3*c1 + c3*s1;
      gs[0]=f2bf(c1); gs[1]=f2bf(c2); gs[2]=f2bf(c3); gs[3]=f2bf(c4);
      gs[4]=f2bf(s1); gs[5]=f2bf(s2); gs[6]=f2bf(s3); gs[7]=f2bf(s4);
    }
    const bf16x8 gf = as_bf(gs);
    short* shb = &shH[bufsel][0];
#pragma unroll
    for (int ct = 0; ct < 2; ++ct) {
      const int colg = 64*w + 32*ct + lo;
      const float av = ct ? a1 : a0;
      // fragment-order BmT: per-g ushort4v load is 64-lane contiguous
      const unsigned short* bt =
          wsU + SBMT_OFF + b*131072 + chunk*8192 + (colg*2 + hl)*4;
      float16 ci;
#pragma unroll
      for (int g = 0; g < 4; ++g) {
        ushort4v v4 = *(const ushort4v*)(bt + g*2048);
        ci[4*g+0] = bf2f(v4[0]) + av;
        ci[4*g+1] = bf2f(v4[1]) + av;
        ci[4*g+2] = bf2f(v4[2]) + av;
        ci[4*g+3] = bf2f(v4[3]) + av;
      }
      ci = __builtin_amdgcn_mfma_f32_32x32x16_bf16(gf, ct ? wg1 : wg0, ci, 0, 0, 0);
      const int ck = colg >> 3;
      float hacc = 0.f;
#pragma unroll
      for (int r = 0; r < 16; ++r) {
        int row = (r&3) + 8*(r>>2) + hl4;
        float sv = silu_f(ci[r]);
        hacc += __shfl(cutv_n, row, 32) * sv;
        shb[row*256 + (((ck ^ row) & 31) << 3) + (colg & 7)] = f2bf(sv);
      }
      if (ct) hs1 += hacc; else hs0 += hacc;
    }
  };

  // prologue: chunk 0 -> buf 0
  phase1(0, 0);
  cutv = cutv_n; pjx = pjx_n; pjy = pjy_n;
  __syncthreads();   // also covers shTbl writes

  for (int k = 0; k < 16; ++k) {
    cs += cutv;

    // ---- coord GEMM, TRANSPOSED: acc2 = W12T-frag * Hs-frag -> D[d][j]
    // col = lane = j (chunk-local lo), row r -> d = 32w + (r&3)+8(r>>2)+hl4
    float16 acc2 = zero16();
    {
      const short* wp = wsS + SW12T_OFF + (32*w + lo)*16 + hl*8;
      const short* shb = &shH[k & 1][0];
#pragma unroll 4
      for (int s = 0; s < 16; ++s) {
        bf16x8 wv = as_bf(*(const short8*)(wp + s*2048));
        const int ck = 2*s + hl;
        bf16x8 af = as_bf(*(const short8*)(shb + lo*256 + (((ck ^ lo) & 31) << 3)));
        acc2 = __builtin_amdgcn_mfma_f32_32x32x16_bf16(wv, af, acc2, 0, 0, 0);
      }
    }

    // ---- phase1 for chunk k+1 -> other buffer (overlaps the GEMM)
    phase1((k + 1) * 32, (k + 1) & 1);

    // ---- epilogue (all lane-local): lane's own j; d indexed by r
    {
      float psum = 0.f;
#pragma unroll
      for (int r = 0; r < 16; ++r) {
        const float4 cst = shTbl[32*w + (r&3) + 8*(r>>2) + hl4];
        psum += silu_f(cutv * (acc2[r] + cst.x) + cst.y) * cst.z + cb2c;
      }
      S += psum;
      SX += psum * pjx;
      SY += psum * pjy;
    }

    cutv = cutv_n; pjx = pjx_n; pjy = pjy_n;
    __syncthreads();   // buf(k+1) writes complete; buf(k) reads complete
  }

  // ---- hsum: merge hl halves, stage to LDS
  hs0 += __shfl_xor(hs0, 32);
  hs1 += __shfl_xor(hs1, 32);
  if (hl == 0) {
    shsum[64*w + lo] = hs0;
    shsum[64*w + 32 + lo] = hs1;
  }

  // ---- cutsum: butterfly within 32 (identical across halves/waves)
  float cutsum = cs;
#pragma unroll
  for (int m = 1; m < 32; m <<= 1) cutsum += __shfl_xor(cutsum, m, 32);

  // ---- S/SX/SY wave reduce
#pragma unroll
  for (int off = 32; off > 0; off >>= 1) {
    S  += __shfl_xor(S, off);
    SX += __shfl_xor(SX, off);
    SY += __shfl_xor(SY, off);
  }
  if (l == 0) { shred[w] = S; shred[4 + w] = SX; shred[8 + w] = SY; }
  __syncthreads();

  // ================= fused node tail (all 256 threads) =================
  float* shIn  = (float*)&shH[0][0];    // 256 floats
  float* shHid = shIn + 256;            // 128 floats
  float* pm    = (float*)&shH[1][0];    // 256 float partials
  const int d  = t & 127, half = t >> 7;

  // ---- msg GEMV partials: pm[t] = sum over half of c' of hsum*ew2T
  {
    const short* er = wsS + SE2T_OFF + d*256 + half*128;
    const float* ss = shsum + half*128;
    float m = 0.f;
#pragma unroll 4
    for (int kk = 0; kk < 16; ++kk) {
      short8 v = *(const short8*)(er + kk*8);
      const float4 s0 = *(const float4*)(ss + kk*8);
      const float4 s1 = *(const float4*)(ss + kk*8 + 4);
      m += bf2f((unsigned short)v[0])*s0.x + bf2f((unsigned short)v[1])*s0.y
         + bf2f((unsigned short)v[2])*s0.z + bf2f((unsigned short)v[3])*s0.w
         + bf2f((unsigned short)v[4])*s1.x + bf2f((unsigned short)v[5])*s1.y
         + bf2f((unsigned short)v[6])*s1.z + bf2f((unsigned short)v[7])*s1.w;
    }
    pm[t] = m;
  }
  if (t == 0) {
    float St  = shred[0] + shred[1] + shred[2]  + shred[3];
    float SXt = shred[4] + shred[5] + shred[6]  + shred[7];
    float SYt = shred[8] + shred[9] + shred[10] + shred[11];
    float updx = pix*St - SXt, updy = piy*St - SYt;
    out[OUT_POS + node*2+0] = pix + updx;
    out[OUT_POS + node*2+1] = piy + updy;
    out[OUT_VEL + node*2+0] = vel[node*2+0] + 0.1f*updx;
    out[OUT_VEL + node*2+1] = vel[node*2+1] + 0.1f*updy;
  }
  __syncthreads();

  // ---- assemble node input: h | msg
  if (t < HID) {
    shIn[t]       = h[node*HID + t];
    shIn[HID + t] = pm[t] + pm[t + 128] + eb2[t] * cutsum;
  }
  __syncthreads();

  // ---- MLP layer 1: pm[t] = sum over half-k of shIn*nw1T (float4 loads)
  {
    const float* wr = ws + WS_N1T + d*256 + half*128;
    const float* si = shIn + half*128;
    float s = 0.f;
#pragma unroll 4
    for (int kk = 0; kk < 32; ++kk) {
      float4 wv = *(const float4*)(wr + kk*4);
      float4 iv = *(const float4*)(si + kk*4);
      s += wv.x*iv.x + wv.y*iv.y + wv.z*iv.z + wv.w*iv.w;
    }
    __syncthreads();   // pm reuse: msg reads done
    pm[t] = s;
  }
  __syncthreads();
  if (t < HID) shHid[t] = silu_f(nb1[t] + pm[t] + pm[t + 128]);
  __syncthreads();

  // ---- MLP layer 2 partials
  {
    const float* wr = ws + WS_N2T + d*128 + half*64;
    const float* si = shHid + half*64;
    float s = 0.f;
#pragma unroll 4
    for (int kk = 0; kk < 16; ++kk) {
      float4 wv = *(const float4*)(wr + kk*4);
      float4 iv = *(const float4*)(si + kk*4);
      s += wv.x*iv.x + wv.y*iv.y + wv.z*iv.z + wv.w*iv.w;
    }
    pm[t] = s;
  }
  __syncthreads();

  // ---- residual + LayerNorm (t < 128)
  float x = 0.f;
  if (t < HID) {
    x = shIn[t] + nb2[t] + pm[t] + pm[t + 128];
    float v1 = x, v2 = x*x;
#pragma unroll
    for (int off = 32; off > 0; off >>= 1) {
      v1 += __shfl_down(v1, off);
      v2 += __shfl_down(v2, off);
    }
    if (l == 0) { shred[w] = v1; shred[2 + w] = v2; }
  }
  __syncthreads();
  if (t < HID) {
    float mu  = (shred[0] + shred[1]) * (1.f/HID);
    float var = (shred[2] + shred[3]) * (1.f/HID) - mu*mu;
    float inv = 1.f / sqrtf(var + 1e-5f);
    out[node*HID + t] = (x - mu) * inv * lng[t] + lnb[t];
  }
}

// ---------------------------------------------------------------- launch
extern "C" void kernel_launch(void* const* d_in, const int* in_sizes, int n_in,
                              void* d_out, int out_size, void* d_ws, size_t ws_size,
                              hipStream_t stream) {
  (void)in_sizes; (void)n_in; (void)out_size; (void)ws_size;
  const float* h   = (const float*)d_in[0];
  const float* pos = (const float*)d_in[1];
  const float* vel = (const float*)d_in[2];
  const float* ew1 = (const float*)d_in[3];
  const float* eb1 = (const float*)d_in[4];
  const float* ew2 = (const float*)d_in[5];
  const float* eb2 = (const float*)d_in[6];
  const float* cw1 = (const float*)d_in[7];
  const float* cb1 = (const float*)d_in[8];
  const float* cw2 = (const float*)d_in[9];
  const float* cb2 = (const float*)d_in[10];
  const float* nw1 = (const float*)d_in[11];
  const float* nb1 = (const float*)d_in[12];
  const float* nw2 = (const float*)d_in[13];
  const float* nb2 = (const float*)d_in[14];
  const float* lng = (const float*)d_in[15];
  const float* lnb = (const float*)d_in[16];
  float* out = (float*)d_out;
  float* ws  = (float*)d_ws;
  unsigned short* wsU = (unsigned short*)d_ws;

  hipLaunchKernelGGL(k01_prep, dim3(721), dim3(256), 0, stream,
                     h, ew1, eb1, ew2, cw1, eb2, nw1, nw2, ws, wsU);
  hipLaunchKernelGGL(k3_edge, dim3(NNODE), dim3(256), 0, stream,
                     pos, vel, h, cb1, cw2, cb2, eb2,
                     nb1, nb2, lng, lnb, ws, out);
}

// Round 5
// 263.091 us; speedup vs baseline: 2.1329x; 1.0176x over previous
//
#include <hip/hip_runtime.h>
#include <math.h>

#define HID 128
#define NN 512
#define NNODE 1024
#define CUTR 10.0f

// ---- ws layout, float offsets
#define WS_A    0            // [1024][256] fp32  (A_i + bias + const-angular row)
#define WS_N1T  262144       // nw1^T fp32 [128][256]
#define WS_N2T  294912       // nw2^T fp32 [128][128]
#define WS_B12  393216       // [128] fp32  eb2 @ cw1
// ---- ws layout, ushort offsets
// BmT fragment-order bf16: [b][chunk16][g4][(col,hl)512][e4]
#define SBMT_OFF  786688                  // 262144 ushorts
#define SE2T_OFF  (SBMT_OFF + 262144)     // ew2^T bf16 [128][256]
// W12T fragment-order bf16: [s16][d128][hl2][e8]
#define SW12T_OFF (SE2T_OFF + 32768)      // 32768 ushorts
#define SW1G_OFF  (SW12T_OFF + 32768)     // W1g^T bf16 [256][16]

// ---- out layout (float offsets)
#define OUT_POS 131072
#define OUT_VEL 133120

typedef __attribute__((ext_vector_type(8)))  short short8;
typedef __attribute__((ext_vector_type(4)))  unsigned short ushort4v;
typedef __attribute__((ext_vector_type(8)))  __bf16 bf16x8;
typedef __attribute__((ext_vector_type(16))) float float16;

__device__ __forceinline__ float silu_f(float x) {
  return x * __builtin_amdgcn_rcpf(1.f + __expf(-x));
}
__device__ __forceinline__ short f2bf(float x) {
  return __builtin_bit_cast(short, (__bf16)x);   // native v_cvt (RNE)
}
__device__ __forceinline__ float bf2f(unsigned short u) {
  union { unsigned u; float f; } v; v.u = ((unsigned)u) << 16;
  return v.f;
}
__device__ __forceinline__ bf16x8 as_bf(short8 s) {
  return __builtin_bit_cast(bf16x8, s);
}
__device__ __forceinline__ float16 zero16() {
  float16 z;
#pragma unroll
  for (int r = 0; r < 16; ++r) z[r] = 0.f;
  return z;
}

// ---------------------------------------------------------------- K01
// ROUND-5: main part re-split to 1 node per block (1024 blocks, 4/CU)
// — was 4 nodes/block x 256 blocks = 1 block/CU, latency-bound (~55us).
// ew1 L2 re-read cost (256MB @ 34.5TB/s ~ 7us) << latency win.
// blocks [1024,1489): weight prep — W12^T (fragment order), ew2^T,
// W1g^T, B12, nw1^T, nw2^T.
__global__ __launch_bounds__(256)
void k01_prep(const float* __restrict__ h, const float* __restrict__ ew1,
              const float* __restrict__ eb1, const float* __restrict__ ew2,
              const float* __restrict__ cw1, const float* __restrict__ eb2,
              const float* __restrict__ nw1, const float* __restrict__ nw2,
              float* __restrict__ ws, unsigned short* __restrict__ wsU) {
  int blk = blockIdx.x;
  int t = threadIdx.x;
  if (blk < 1024) {
    __shared__ float sh_h[HID];
    const int node = blk;
    if (t < HID) sh_h[t] = h[node*HID + t];
    __syncthreads();
    const int c = t;
    float a = eb1[c] + ew1[264*256 + c];   // bias + const-angular row
    float bm = 0.f;
#pragma unroll 8
    for (int k = 0; k < HID; ++k) {
      float hk = sh_h[k];
      a  += hk * ew1[k*256 + c];
      bm += hk * ew1[(128+k)*256 + c];
    }
    ws[WS_A + node*256 + c] = a;
    const int b = node >> 9, j = node & 511;
    const int chunk = j >> 5, jr = j & 31;
    const int e = jr & 3, hlw = (jr >> 2) & 1, g = jr >> 3;
    wsU[SBMT_OFF + b*131072 + chunk*8192 + g*2048 + (c*2 + hlw)*4 + e] =
        (unsigned short)f2bf(bm);
  } else {
    int idx = (blk - 1024) * 256 + t;
    if (idx < 32768) {
      // W12T[d][cp] = sum_c ew2[cp][c] * cw1[c][d], fragment-order store
      int d = idx & 127, cp = idx >> 7;
      float s = 0.f;
#pragma unroll 4
      for (int c = 0; c < 128; ++c) s += ew2[cp*128 + c] * cw1[c*128 + d];
      int sg = cp >> 4, hlw = (cp >> 3) & 1, e = cp & 7;
      wsU[SW12T_OFF + sg*2048 + d*16 + hlw*8 + e] = (unsigned short)f2bf(s);
    } else if (idx < 65536) {
      int i2 = idx - 32768; int c = i2 >> 8, k = i2 & 255;
      wsU[SE2T_OFF + c*256 + k] = (unsigned short)f2bf(ew2[k*HID + c]);
    } else if (idx < 69632) {
      int i3 = idx - 65536; int c = i3 >> 4, f = i3 & 15;
      int row = (f < 8) ? (256 + f) : (257 + f);
      wsU[SW1G_OFF + c*16 + f] = (unsigned short)f2bf(ew1[row*256 + c]);
    } else if (idx < 69760) {
      int d = idx - 69632;
      float s = 0.f;
#pragma unroll 4
      for (int c = 0; c < 128; ++c) s += eb2[c] * cw1[c*128 + d];
      ws[WS_B12 + d] = s;
    } else if (idx < 102528) {
      int i4 = idx - 69760; int d = i4 >> 8, k = i4 & 255;
      ws[WS_N1T + d*256 + k] = nw1[k*HID + d];
    } else if (idx < 118912) {
      int i5 = idx - 102528; int d = i5 >> 7, k = i5 & 127;
      ws[WS_N2T + d*128 + k] = nw2[k*HID + d];
    }
  }
}

// ---------------------------------------------------------------- K3
// One block per (b,i); 4 waves. r4 structure (208us) + ROUND-5:
//  - shCut LDS broadcast table replaces 32 ds_bpermute/iter in phase1
//    (row is uniform-per-half: addr = invariant reg + imm offset)
//  - pos staged to LDS once (4KB): per-iter geometry loads 500cyc->120cyc
//  - epilogue cb2c folded out of r-loop (16 adds -> 1)
// REGISTER LAW (r0/r1/r2): ~220 unified regs -> 2 waves/SIMD tier.
// launch_bounds(256,3) spills w/o occupancy gain (r2); (512,4)
// catastrophic (r1). Do NOT re-attempt occupancy tiers or add state.
__global__ __launch_bounds__(256)
void k3_edge(const float* __restrict__ pos, const float* __restrict__ vel,
             const float* __restrict__ h,
             const float* __restrict__ cb1, const float* __restrict__ cw2,
             const float* __restrict__ cb2, const float* __restrict__ eb2,
             const float* __restrict__ nb1, const float* __restrict__ nb2,
             const float* __restrict__ lng, const float* __restrict__ lnb,
             float* __restrict__ ws, float* __restrict__ out) {
  const short* wsS = (const short*)ws;
  const unsigned short* wsU = (const unsigned short*)ws;
  __shared__ __align__(16) short shH[2][32*256];  // bf16, xor-swizzled, double-buffered
  __shared__ float shsum[256];
  __shared__ float shred[12];
  __shared__ float4 shTbl[128];                   // {B12[d], cb1[d], cw2[d], 0}
  __shared__ __align__(16) float2 shPos[NN];      // batch positions
  __shared__ float shCut[32];                     // per-chunk cut broadcast

  const int t = threadIdx.x;
  const int w = t >> 6, l = t & 63, lo = l & 31, hl = l >> 5, hl4 = hl * 4;
  const int node = blockIdx.x;
  const int b = node >> 9;
  const int bN = b * NN;

  const bf16x8 wg0 = as_bf(*(const short8*)(wsS + SW1G_OFF + (64*w + lo)*16 + hl*8));
  const bf16x8 wg1 = as_bf(*(const short8*)(wsS + SW1G_OFF + (64*w + 32 + lo)*16 + hl*8));

  const float a0   = ws[WS_A + node*256 + 64*w + lo];
  const float a1   = ws[WS_A + node*256 + 64*w + 32 + lo];
  const float cb2c16 = cb2[0] * (16.f/128.f);
  const float pix  = pos[node*2], piy = pos[node*2+1];

  // stage pos (4KB) + fold table, once
  ((float4*)shPos)[t] = ((const float4*)(pos + 2*bN))[t];
  if (t < 128) shTbl[t] = make_float4(ws[WS_B12 + t], cb1[t], cw2[t], 0.f);
  __syncthreads();

  float hs0 = 0.f, hs1 = 0.f;    // hsum partials for cols 64w+lo, 64w+32+lo
  float cs = 0.f;                // sum_j cut_j (per-lane over own j's)
  float S = 0.f, SX = 0.f, SY = 0.f;
  float cutv, pjx, pjy;
  float cutv_n, pjx_n, pjy_n;

  auto phase1 = [&](int jbw, int bufsel) {
    const int jb = jbw & (NN - 1);
    const int chunk = jb >> 5;
    const float2 pj = shPos[jb + lo];
    pjx_n = pj.x; pjy_n = pj.y;
    const float dx = pix - pjx_n, dy = piy - pjy_n;
    const float d = sqrtf(dx*dx + dy*dy);
    cutv_n = (d < CUTR) ? 0.5f*(__cosf((float)M_PI*(1.f/CUTR)*d) + 1.f) : 0.f;
    if (jbw >= NN) cutv_n = 0.f;
    // publish cut for broadcast reads (all waves write identical values;
    // same-wave DS ordering guarantees our own reads see it)
    if (hl == 0) shCut[lo] = cutv_n;
    short8 gs;
    if (hl == 0) {
#pragma unroll
      for (int k = 0; k < 8; ++k) {
        float ctr = (CUTR * (float)k) / 7.0f;
        float tt = (d - ctr) * 0.8f;
        gs[k] = f2bf(__expf(-tt*tt));
      }
    } else {
      float invd = __builtin_amdgcn_rcpf(d + 1e-8f);
      float c1 = dx * invd, s1 = dy * invd;
      if (d == 0.f) { c1 = 1.f; s1 = 0.f; }
      float c2 = c1*c1 - s1*s1, s2 = 2.f*s1*c1;
      float c3 = c2*c1 - s2*s1, s3 = s2*c1 + c2*s1;
      float c4 = c3*c1 - s3*s1, s4 = s3*c1 + c3*s1;
      gs[0]=f2bf(c1); gs[1]=f2bf(c2); gs[2]=f2bf(c3); gs[3]=f2bf(c4);
      gs[4]=f2bf(s1); gs[5]=f2bf(s2); gs[6]=f2bf(s3); gs[7]=f2bf(s4);
    }
    const bf16x8 gf = as_bf(gs);
    short* shb = &shH[bufsel][0];
#pragma unroll
    for (int ct = 0; ct < 2; ++ct) {
      const int colg = 64*w + 32*ct + lo;
      const float av = ct ? a1 : a0;
      // fragment-order BmT: per-g ushort4v load is 64-lane contiguous
      const unsigned short* bt =
          wsU + SBMT_OFF + b*131072 + chunk*8192 + (colg*2 + hl)*4;
      float16 ci;
#pragma unroll
      for (int g = 0; g < 4; ++g) {
        ushort4v v4 = *(const ushort4v*)(bt + g*2048);
        ci[4*g+0] = bf2f(v4[0]) + av;
        ci[4*g+1] = bf2f(v4[1]) + av;
        ci[4*g+2] = bf2f(v4[2]) + av;
        ci[4*g+3] = bf2f(v4[3]) + av;
      }
      ci = __builtin_amdgcn_mfma_f32_32x32x16_bf16(gf, ct ? wg1 : wg0, ci, 0, 0, 0);
      const int ck = colg >> 3;
      float hacc = 0.f;
#pragma unroll
      for (int r = 0; r < 16; ++r) {
        int row = (r&3) + 8*(r>>2) + hl4;
        float sv = silu_f(ci[r]);
        hacc += shCut[row] * sv;    // broadcast ds_read (imm offset)
        shb[row*256 + (((ck ^ row) & 31) << 3) + (colg & 7)] = f2bf(sv);
      }
      if (ct) hs1 += hacc; else hs0 += hacc;
    }
  };

  // prologue: chunk 0 -> buf 0
  phase1(0, 0);
  cutv = cutv_n; pjx = pjx_n; pjy = pjy_n;
  __syncthreads();

  for (int k = 0; k < 16; ++k) {
    cs += cutv;

    // ---- coord GEMM, transposed: acc2 = W12T-frag * Hs-frag -> D[d][j]
    float16 acc2 = zero16();
    {
      const short* wp = wsS + SW12T_OFF + (32*w + lo)*16 + hl*8;
      const short* shb = &shH[k & 1][0];
#pragma unroll 4
      for (int s = 0; s < 16; ++s) {
        bf16x8 wv = as_bf(*(const short8*)(wp + s*2048));
        const int ck = 2*s + hl;
        bf16x8 af = as_bf(*(const short8*)(shb + lo*256 + (((ck ^ lo) & 31) << 3)));
        acc2 = __builtin_amdgcn_mfma_f32_32x32x16_bf16(wv, af, acc2, 0, 0, 0);
      }
    }

    // ---- phase1 for chunk k+1 -> other buffer (overlaps the GEMM)
    phase1((k + 1) * 32, (k + 1) & 1);

    // ---- epilogue (all lane-local): lane's own j; d indexed by r
    {
      float psum = 0.f;
#pragma unroll
      for (int r = 0; r < 16; ++r) {
        const float4 cst = shTbl[32*w + (r&3) + 8*(r>>2) + hl4];
        psum += silu_f(cutv * (acc2[r] + cst.x) + cst.y) * cst.z;
      }
      psum += cb2c16;
      S += psum;
      SX += psum * pjx;
      SY += psum * pjy;
    }

    cutv = cutv_n; pjx = pjx_n; pjy = pjy_n;
    __syncthreads();   // buf(k+1) writes complete; buf(k) reads complete
  }

  // ---- hsum: merge hl halves, stage to LDS
  hs0 += __shfl_xor(hs0, 32);
  hs1 += __shfl_xor(hs1, 32);
  if (hl == 0) {
    shsum[64*w + lo] = hs0;
    shsum[64*w + 32 + lo] = hs1;
  }

  // ---- cutsum: butterfly within 32 (identical across halves/waves)
  float cutsum = cs;
#pragma unroll
  for (int m = 1; m < 32; m <<= 1) cutsum += __shfl_xor(cutsum, m, 32);

  // ---- S/SX/SY wave reduce
#pragma unroll
  for (int off = 32; off > 0; off >>= 1) {
    S  += __shfl_xor(S, off);
    SX += __shfl_xor(SX, off);
    SY += __shfl_xor(SY, off);
  }
  if (l == 0) { shred[w] = S; shred[4 + w] = SX; shred[8 + w] = SY; }
  __syncthreads();

  // ================= fused node tail (all 256 threads) =================
  float* shIn  = (float*)&shH[0][0];    // 256 floats
  float* shHid = shIn + 256;            // 128 floats
  float* pm    = (float*)&shH[1][0];    // 256 float partials
  const int d  = t & 127, half = t >> 7;

  // ---- msg GEMV partials: pm[t] = sum over half of c' of hsum*ew2T
  {
    const short* er = wsS + SE2T_OFF + d*256 + half*128;
    const float* ss = shsum + half*128;
    float m = 0.f;
#pragma unroll 4
    for (int kk = 0; kk < 16; ++kk) {
      short8 v = *(const short8*)(er + kk*8);
      const float4 s0 = *(const float4*)(ss + kk*8);
      const float4 s1 = *(const float4*)(ss + kk*8 + 4);
      m += bf2f((unsigned short)v[0])*s0.x + bf2f((unsigned short)v[1])*s0.y
         + bf2f((unsigned short)v[2])*s0.z + bf2f((unsigned short)v[3])*s0.w
         + bf2f((unsigned short)v[4])*s1.x + bf2f((unsigned short)v[5])*s1.y
         + bf2f((unsigned short)v[6])*s1.z + bf2f((unsigned short)v[7])*s1.w;
    }
    pm[t] = m;
  }
  if (t == 0) {
    float St  = shred[0] + shred[1] + shred[2]  + shred[3];
    float SXt = shred[4] + shred[5] + shred[6]  + shred[7];
    float SYt = shred[8] + shred[9] + shred[10] + shred[11];
    float updx = pix*St - SXt, updy = piy*St - SYt;
    out[OUT_POS + node*2+0] = pix + updx;
    out[OUT_POS + node*2+1] = piy + updy;
    out[OUT_VEL + node*2+0] = vel[node*2+0] + 0.1f*updx;
    out[OUT_VEL + node*2+1] = vel[node*2+1] + 0.1f*updy;
  }
  __syncthreads();

  // ---- assemble node input: h | msg
  if (t < HID) {
    shIn[t]       = h[node*HID + t];
    shIn[HID + t] = pm[t] + pm[t + 128] + eb2[t] * cutsum;
  }
  __syncthreads();

  // ---- MLP layer 1: pm[t] = sum over half-k of shIn*nw1T (float4 loads)
  {
    const float* wr = ws + WS_N1T + d*256 + half*128;
    const float* si = shIn + half*128;
    float s = 0.f;
#pragma unroll 4
    for (int kk = 0; kk < 32; ++kk) {
      float4 wv = *(const float4*)(wr + kk*4);
      float4 iv = *(const float4*)(si + kk*4);
      s += wv.x*iv.x + wv.y*iv.y + wv.z*iv.z + wv.w*iv.w;
    }
    __syncthreads();   // pm reuse: msg reads done
    pm[t] = s;
  }
  __syncthreads();
  if (t < HID) shHid[t] = silu_f(nb1[t] + pm[t] + pm[t + 128]);
  __syncthreads();

  // ---- MLP layer 2 partials
  {
    const float* wr = ws + WS_N2T + d*128 + half*64;
    const float* si = shHid + half*64;
    float s = 0.f;
#pragma unroll 4
    for (int kk = 0; kk < 16; ++kk) {
      float4 wv = *(const float4*)(wr + kk*4);
      float4 iv = *(const float4*)(si + kk*4);
      s += wv.x*iv.x + wv.y*iv.y + wv.z*iv.z + wv.w*iv.w;
    }
    pm[t] = s;
  }
  __syncthreads();

  // ---- residual + LayerNorm (t < 128)
  float x = 0.f;
  if (t < HID) {
    x = shIn[t] + nb2[t] + pm[t] + pm[t + 128];
    float v1 = x, v2 = x*x;
#pragma unroll
    for (int off = 32; off > 0; off >>= 1) {
      v1 += __shfl_down(v1, off);
      v2 += __shfl_down(v2, off);
    }
    if (l == 0) { shred[w] = v1; shred[2 + w] = v2; }
  }
  __syncthreads();
  if (t < HID) {
    float mu  = (shred[0] + shred[1]) * (1.f/HID);
    float var = (shred[2] + shred[3]) * (1.f/HID) - mu*mu;
    float inv = 1.f / sqrtf(var + 1e-5f);
    out[node*HID + t] = (x - mu) * inv * lng[t] + lnb[t];
  }
}

// ---------------------------------------------------------------- launch
extern "C" void kernel_launch(void* const* d_in, const int* in_sizes, int n_in,
                              void* d_out, int out_size, void* d_ws, size_t ws_size,
                              hipStream_t stream) {
  (void)in_sizes; (void)n_in; (void)out_size; (void)ws_size;
  const float* h   = (const float*)d_in[0];
  const float* pos = (const float*)d_in[1];
  const float* vel = (const float*)d_in[2];
  const float* ew1 = (const float*)d_in[3];
  const float* eb1 = (const float*)d_in[4];
  const float* ew2 = (const float*)d_in[5];
  const float* eb2 = (const float*)d_in[6];
  const float* cw1 = (const float*)d_in[7];
  const float* cb1 = (const float*)d_in[8];
  const float* cw2 = (const float*)d_in[9];
  const float* cb2 = (const float*)d_in[10];
  const float* nw1 = (const float*)d_in[11];
  const float* nb1 = (const float*)d_in[12];
  const float* nw2 = (const float*)d_in[13];
  const float* nb2 = (const float*)d_in[14];
  const float* lng = (const float*)d_in[15];
  const float* lnb = (const float*)d_in[16];
  float* out = (float*)d_out;
  float* ws  = (float*)d_ws;
  unsigned short* wsU = (unsigned short*)d_ws;

  hipLaunchKernelGGL(k01_prep, dim3(1489), dim3(256), 0, stream,
                     h, ew1, eb1, ew2, cw1, eb2, nw1, nw2, ws, wsU);
  hipLaunchKernelGGL(k3_edge, dim3(NNODE), dim3(256), 0, stream,
                     pos, vel, h, cb1, cw2, cb2, eb2,
                     nb1, nb2, lng, lnb, ws, out);
}

// Round 8
// 259.244 us; speedup vs baseline: 2.1645x; 1.0148x over previous
//
#include <hip/hip_runtime.h>
#include <math.h>

#define HID 128
#define NN 512
#define NNODE 1024
#define CUTR 10.0f

// ---- ws layout, float offsets
#define WS_A    0            // [1024][256] fp32  (A_i + bias + const-angular row)
#define WS_N1T  262144       // nw1^T fp32 [128][256]
#define WS_N2T  294912       // nw2^T fp32 [128][128]
#define WS_B12  393216       // [128] fp32  eb2 @ cw1
// ---- ws layout, ushort offsets
// BmT fragment-order bf16: [b][chunk16][g4][(col,hl)512][e4]
#define SBMT_OFF  786688                  // 262144 ushorts
#define SE2T_OFF  (SBMT_OFF + 262144)     // ew2^T bf16 [128][256]
// W12T fragment-order bf16: [s16][d128][hl2][e8]
#define SW12T_OFF (SE2T_OFF + 32768)      // 32768 ushorts
#define SW1G_OFF  (SW12T_OFF + 32768)     // W1g^T bf16 [256][16]

// ---- out layout (float offsets)
#define OUT_POS 131072
#define OUT_VEL 133120

typedef __attribute__((ext_vector_type(8)))  short short8;
typedef __attribute__((ext_vector_type(4)))  unsigned short ushort4v;
typedef __attribute__((ext_vector_type(8)))  __bf16 bf16x8;
typedef __attribute__((ext_vector_type(16))) float float16;

__device__ __forceinline__ float silu_f(float x) {
  return x * __builtin_amdgcn_rcpf(1.f + __expf(-x));
}
__device__ __forceinline__ short f2bf(float x) {
  return __builtin_bit_cast(short, (__bf16)x);   // native v_cvt (RNE)
}
__device__ __forceinline__ float bf2f(unsigned short u) {
  union { unsigned u; float f; } v; v.u = ((unsigned)u) << 16;
  return v.f;
}
__device__ __forceinline__ bf16x8 as_bf(short8 s) {
  return __builtin_bit_cast(bf16x8, s);
}
__device__ __forceinline__ float16 zero16() {
  float16 z;
#pragma unroll
  for (int r = 0; r < 16; ++r) z[r] = 0.f;
  return z;
}

// ---------------------------------------------------------------- K01
// ROUND-8: split-bf16 MFMA GEMM for A/Bm, with the r6/r7 BUG FIXED:
// the B-frag column for Bm tiles was ubase+lo (>=256) which wrapped into
// ew1's NEXT ROW (only 256 cols) — Bm used weight rows 129..256 instead
// of 128..255. r6 vs r7 bit-identical error proved precision-independent
// (deterministic mapping bug). Fix: ucol = (ubase & 255) + lo for the
// ew1 column on BOTH load and store.
// Split-bf16 (x = hi + lo, 3 MFMAs/K-step) kept for fp32-class A.
// 128 blocks x 4 waves; wave = one 32node x 32ucol tile;
// u<256 -> A (f32+bias store), u>=256 -> Bm (bf16, k3 fragment order).
// blocks [128,593): weight prep (unchanged).
__global__ __launch_bounds__(256)
void k01_prep(const float* __restrict__ h, const float* __restrict__ ew1,
              const float* __restrict__ eb1, const float* __restrict__ ew2,
              const float* __restrict__ cw1, const float* __restrict__ eb2,
              const float* __restrict__ nw1, const float* __restrict__ nw2,
              float* __restrict__ ws, unsigned short* __restrict__ wsU) {
  int blk = blockIdx.x;
  int t = threadIdx.x;
  if (blk < 128) {
    const int w = t >> 6, l = t & 63, lo = l & 31, hl = l >> 5;
    const int tile  = blk * 4 + w;       // 0..511
    const int nbase = (tile >> 4) * 32;  // node tile base (32-aligned)
    const int ubase = (tile & 15) * 32;  // output-col tile base (0..511)
    const bool isA  = (ubase < 256);
    const int krow0 = isA ? 0 : 128;     // ew1 k-row base
    const int ucol  = (ubase & 255) + lo;  // ew1 COLUMN (0..255) — r7 bugfix

    float16 acc = zero16();
    const float* hrow = h + (nbase + lo) * HID;   // A-frag row = lane's node
#pragma unroll
    for (int s = 0; s < 8; ++s) {
      // A-frag: h[nbase+lo][16s + hl*8 + e], split hi/lo bf16
      const float* hp = hrow + 16 * s + hl * 8;
      float4 h0 = *(const float4*)(hp);
      float4 h1 = *(const float4*)(hp + 4);
      float av[8] = {h0.x, h0.y, h0.z, h0.w, h1.x, h1.y, h1.z, h1.w};
      short8 ah, al;
#pragma unroll
      for (int e = 0; e < 8; ++e) {
        ah[e] = f2bf(av[e]);
        al[e] = f2bf(av[e] - bf2f((unsigned short)ah[e]));
      }
      // B-frag: ew1[krow0 + 16s + hl*8 + e][ucol], split hi/lo bf16
      short8 bh, bl;
#pragma unroll
      for (int e = 0; e < 8; ++e) {
        float x = ew1[(krow0 + 16*s + hl*8 + e) * 256 + ucol];
        bh[e] = f2bf(x);
        bl[e] = f2bf(x - bf2f((unsigned short)bh[e]));
      }
      acc = __builtin_amdgcn_mfma_f32_32x32x16_bf16(as_bf(ah), as_bf(bh), acc, 0, 0, 0);
      acc = __builtin_amdgcn_mfma_f32_32x32x16_bf16(as_bf(ah), as_bf(bl), acc, 0, 0, 0);
      acc = __builtin_amdgcn_mfma_f32_32x32x16_bf16(as_bf(al), as_bf(bh), acc, 0, 0, 0);
    }

    // epilogue: C layout reg r -> row n = (r&3)+8*(r>>2)+4*hl, col = lo
    if (isA) {
      const float bias = eb1[ucol] + ew1[264*256 + ucol];
#pragma unroll
      for (int r = 0; r < 16; ++r) {
        const int n = (r & 3) + 8 * (r >> 2) + 4 * hl;
        ws[WS_A + (nbase + n) * 256 + ucol] = acc[r] + bias;
      }
    } else {
      const int bb = nbase >> 9;
      const int chunk = (nbase & 511) >> 5;
      // j-rel = n: e = r&3, g = r>>2, hlB = hl  (decomposition verified)
      const int base = SBMT_OFF + bb*131072 + chunk*8192 + (ucol*2 + hl)*4;
#pragma unroll
      for (int r = 0; r < 16; ++r)
        wsU[base + (r >> 2) * 2048 + (r & 3)] = (unsigned short)f2bf(acc[r]);
    }
  } else {
    int idx = (blk - 128) * 256 + t;
    if (idx < 32768) {
      // W12T[d][cp] = sum_c ew2[cp][c] * cw1[c][d], fragment-order store
      int d = idx & 127, cp = idx >> 7;
      float s = 0.f;
#pragma unroll 4
      for (int c = 0; c < 128; ++c) s += ew2[cp*128 + c] * cw1[c*128 + d];
      int sg = cp >> 4, hlw = (cp >> 3) & 1, e = cp & 7;
      wsU[SW12T_OFF + sg*2048 + d*16 + hlw*8 + e] = (unsigned short)f2bf(s);
    } else if (idx < 65536) {
      int i2 = idx - 32768; int c = i2 >> 8, k = i2 & 255;
      wsU[SE2T_OFF + c*256 + k] = (unsigned short)f2bf(ew2[k*HID + c]);
    } else if (idx < 69632) {
      int i3 = idx - 65536; int c = i3 >> 4, f = i3 & 15;
      int row = (f < 8) ? (256 + f) : (257 + f);
      wsU[SW1G_OFF + c*16 + f] = (unsigned short)f2bf(ew1[row*256 + c]);
    } else if (idx < 69760) {
      int d = idx - 69632;
      float s = 0.f;
#pragma unroll 4
      for (int c = 0; c < 128; ++c) s += eb2[c] * cw1[c*128 + d];
      ws[WS_B12 + d] = s;
    } else if (idx < 102528) {
      int i4 = idx - 69760; int d = i4 >> 8, k = i4 & 255;
      ws[WS_N1T + d*256 + k] = nw1[k*HID + d];
    } else if (idx < 118912) {
      int i5 = idx - 102528; int d = i5 >> 7, k = i5 & 127;
      ws[WS_N2T + d*128 + k] = nw2[k*HID + d];
    }
  }
}

// ---------------------------------------------------------------- K3
// One block per (b,i); 4 waves. UNCHANGED from r5 (191.5us):
//  - fragment-order coalesced BmT/W12T streams (r3, the big win)
//  - transposed coord-GEMM, lane-local epilogue (r4)
//  - shCut broadcast table, pos in LDS (r5)
// REGISTER LAW (r0/r1/r2): ~220 unified regs -> 2 waves/SIMD tier.
// launch_bounds(256,3) spills w/o occupancy gain (r2); (512,4)
// catastrophic (r1). Do NOT re-attempt occupancy tiers or add state.
__global__ __launch_bounds__(256)
void k3_edge(const float* __restrict__ pos, const float* __restrict__ vel,
             const float* __restrict__ h,
             const float* __restrict__ cb1, const float* __restrict__ cw2,
             const float* __restrict__ cb2, const float* __restrict__ eb2,
             const float* __restrict__ nb1, const float* __restrict__ nb2,
             const float* __restrict__ lng, const float* __restrict__ lnb,
             float* __restrict__ ws, float* __restrict__ out) {
  const short* wsS = (const short*)ws;
  const unsigned short* wsU = (const unsigned short*)ws;
  __shared__ __align__(16) short shH[2][32*256];  // bf16, xor-swizzled, double-buffered
  __shared__ float shsum[256];
  __shared__ float shred[12];
  __shared__ float4 shTbl[128];                   // {B12[d], cb1[d], cw2[d], 0}
  __shared__ __align__(16) float2 shPos[NN];      // batch positions
  __shared__ float shCut[32];                     // per-chunk cut broadcast

  const int t = threadIdx.x;
  const int w = t >> 6, l = t & 63, lo = l & 31, hl = l >> 5, hl4 = hl * 4;
  const int node = blockIdx.x;
  const int b = node >> 9;
  const int bN = b * NN;

  const bf16x8 wg0 = as_bf(*(const short8*)(wsS + SW1G_OFF + (64*w + lo)*16 + hl*8));
  const bf16x8 wg1 = as_bf(*(const short8*)(wsS + SW1G_OFF + (64*w + 32 + lo)*16 + hl*8));

  const float a0   = ws[WS_A + node*256 + 64*w + lo];
  const float a1   = ws[WS_A + node*256 + 64*w + 32 + lo];
  const float cb2c16 = cb2[0] * (16.f/128.f);
  const float pix  = pos[node*2], piy = pos[node*2+1];

  // stage pos (4KB) + fold table, once
  ((float4*)shPos)[t] = ((const float4*)(pos + 2*bN))[t];
  if (t < 128) shTbl[t] = make_float4(ws[WS_B12 + t], cb1[t], cw2[t], 0.f);
  __syncthreads();

  float hs0 = 0.f, hs1 = 0.f;    // hsum partials for cols 64w+lo, 64w+32+lo
  float cs = 0.f;                // sum_j cut_j (per-lane over own j's)
  float S = 0.f, SX = 0.f, SY = 0.f;
  float cutv, pjx, pjy;
  float cutv_n, pjx_n, pjy_n;

  auto phase1 = [&](int jbw, int bufsel) {
    const int jb = jbw & (NN - 1);
    const int chunk = jb >> 5;
    const float2 pj = shPos[jb + lo];
    pjx_n = pj.x; pjy_n = pj.y;
    const float dx = pix - pjx_n, dy = piy - pjy_n;
    const float d = sqrtf(dx*dx + dy*dy);
    cutv_n = (d < CUTR) ? 0.5f*(__cosf((float)M_PI*(1.f/CUTR)*d) + 1.f) : 0.f;
    if (jbw >= NN) cutv_n = 0.f;
    // publish cut for broadcast reads (all waves write identical values;
    // same-wave DS ordering guarantees our own reads see it)
    if (hl == 0) shCut[lo] = cutv_n;
    short8 gs;
    if (hl == 0) {
#pragma unroll
      for (int k = 0; k < 8; ++k) {
        float ctr = (CUTR * (float)k) / 7.0f;
        float tt = (d - ctr) * 0.8f;
        gs[k] = f2bf(__expf(-tt*tt));
      }
    } else {
      float invd = __builtin_amdgcn_rcpf(d + 1e-8f);
      float c1 = dx * invd, s1 = dy * invd;
      if (d == 0.f) { c1 = 1.f; s1 = 0.f; }
      float c2 = c1*c1 - s1*s1, s2 = 2.f*s1*c1;
      float c3 = c2*c1 - s2*s1, s3 = s2*c1 + c2*s1;
      float c4 = c3*c1 - s3*s1, s4 = s3*c1 + c3*s1;
      gs[0]=f2bf(c1); gs[1]=f2bf(c2); gs[2]=f2bf(c3); gs[3]=f2bf(c4);
      gs[4]=f2bf(s1); gs[5]=f2bf(s2); gs[6]=f2bf(s3); gs[7]=f2bf(s4);
    }
    const bf16x8 gf = as_bf(gs);
    short* shb = &shH[bufsel][0];
#pragma unroll
    for (int ct = 0; ct < 2; ++ct) {
      const int colg = 64*w + 32*ct + lo;
      const float av = ct ? a1 : a0;
      // fragment-order BmT: per-g ushort4v load is 64-lane contiguous
      const unsigned short* bt =
          wsU + SBMT_OFF + b*131072 + chunk*8192 + (colg*2 + hl)*4;
      float16 ci;
#pragma unroll
      for (int g = 0; g < 4; ++g) {
        ushort4v v4 = *(const ushort4v*)(bt + g*2048);
        ci[4*g+0] = bf2f(v4[0]) + av;
        ci[4*g+1] = bf2f(v4[1]) + av;
        ci[4*g+2] = bf2f(v4[2]) + av;
        ci[4*g+3] = bf2f(v4[3]) + av;
      }
      ci = __builtin_amdgcn_mfma_f32_32x32x16_bf16(gf, ct ? wg1 : wg0, ci, 0, 0, 0);
      const int ck = colg >> 3;
      float hacc = 0.f;
#pragma unroll
      for (int r = 0; r < 16; ++r) {
        int row = (r&3) + 8*(r>>2) + hl4;
        float sv = silu_f(ci[r]);
        hacc += shCut[row] * sv;    // broadcast ds_read (imm offset)
        shb[row*256 + (((ck ^ row) & 31) << 3) + (colg & 7)] = f2bf(sv);
      }
      if (ct) hs1 += hacc; else hs0 += hacc;
    }
  };

  // prologue: chunk 0 -> buf 0
  phase1(0, 0);
  cutv = cutv_n; pjx = pjx_n; pjy = pjy_n;
  __syncthreads();

  for (int k = 0; k < 16; ++k) {
    cs += cutv;

    // ---- coord GEMM, transposed: acc2 = W12T-frag * Hs-frag -> D[d][j]
    float16 acc2 = zero16();
    {
      const short* wp = wsS + SW12T_OFF + (32*w + lo)*16 + hl*8;
      const short* shb = &shH[k & 1][0];
#pragma unroll 4
      for (int s = 0; s < 16; ++s) {
        bf16x8 wv = as_bf(*(const short8*)(wp + s*2048));
        const int ck = 2*s + hl;
        bf16x8 af = as_bf(*(const short8*)(shb + lo*256 + (((ck ^ lo) & 31) << 3)));
        acc2 = __builtin_amdgcn_mfma_f32_32x32x16_bf16(wv, af, acc2, 0, 0, 0);
      }
    }

    // ---- phase1 for chunk k+1 -> other buffer (overlaps the GEMM)
    phase1((k + 1) * 32, (k + 1) & 1);

    // ---- epilogue (all lane-local): lane's own j; d indexed by r
    {
      float psum = 0.f;
#pragma unroll
      for (int r = 0; r < 16; ++r) {
        const float4 cst = shTbl[32*w + (r&3) + 8*(r>>2) + hl4];
        psum += silu_f(cutv * (acc2[r] + cst.x) + cst.y) * cst.z;
      }
      psum += cb2c16;
      S += psum;
      SX += psum * pjx;
      SY += psum * pjy;
    }

    cutv = cutv_n; pjx = pjx_n; pjy = pjy_n;
    __syncthreads();   // buf(k+1) writes complete; buf(k) reads complete
  }

  // ---- hsum: merge hl halves, stage to LDS
  hs0 += __shfl_xor(hs0, 32);
  hs1 += __shfl_xor(hs1, 32);
  if (hl == 0) {
    shsum[64*w + lo] = hs0;
    shsum[64*w + 32 + lo] = hs1;
  }

  // ---- cutsum: butterfly within 32 (identical across halves/waves)
  float cutsum = cs;
#pragma unroll
  for (int m = 1; m < 32; m <<= 1) cutsum += __shfl_xor(cutsum, m, 32);

  // ---- S/SX/SY wave reduce
#pragma unroll
  for (int off = 32; off > 0; off >>= 1) {
    S  += __shfl_xor(S, off);
    SX += __shfl_xor(SX, off);
    SY += __shfl_xor(SY, off);
  }
  if (l == 0) { shred[w] = S; shred[4 + w] = SX; shred[8 + w] = SY; }
  __syncthreads();

  // ================= fused node tail (all 256 threads) =================
  float* shIn  = (float*)&shH[0][0];    // 256 floats
  float* shHid = shIn + 256;            // 128 floats
  float* pm    = (float*)&shH[1][0];    // 256 float partials
  const int d  = t & 127, half = t >> 7;

  // ---- msg GEMV partials: pm[t] = sum over half of c' of hsum*ew2T
  {
    const short* er = wsS + SE2T_OFF + d*256 + half*128;
    const float* ss = shsum + half*128;
    float m = 0.f;
#pragma unroll 4
    for (int kk = 0; kk < 16; ++kk) {
      short8 v = *(const short8*)(er + kk*8);
      const float4 s0 = *(const float4*)(ss + kk*8);
      const float4 s1 = *(const float4*)(ss + kk*8 + 4);
      m += bf2f((unsigned short)v[0])*s0.x + bf2f((unsigned short)v[1])*s0.y
         + bf2f((unsigned short)v[2])*s0.z + bf2f((unsigned short)v[3])*s0.w
         + bf2f((unsigned short)v[4])*s1.x + bf2f((unsigned short)v[5])*s1.y
         + bf2f((unsigned short)v[6])*s1.z + bf2f((unsigned short)v[7])*s1.w;
    }
    pm[t] = m;
  }
  if (t == 0) {
    float St  = shred[0] + shred[1] + shred[2]  + shred[3];
    float SXt = shred[4] + shred[5] + shred[6]  + shred[7];
    float SYt = shred[8] + shred[9] + shred[10] + shred[11];
    float updx = pix*St - SXt, updy = piy*St - SYt;
    out[OUT_POS + node*2+0] = pix + updx;
    out[OUT_POS + node*2+1] = piy + updy;
    out[OUT_VEL + node*2+0] = vel[node*2+0] + 0.1f*updx;
    out[OUT_VEL + node*2+1] = vel[node*2+1] + 0.1f*updy;
  }
  __syncthreads();

  // ---- assemble node input: h | msg
  if (t < HID) {
    shIn[t]       = h[node*HID + t];
    shIn[HID + t] = pm[t] + pm[t + 128] + eb2[t] * cutsum;
  }
  __syncthreads();

  // ---- MLP layer 1: pm[t] = sum over half-k of shIn*nw1T (float4 loads)
  {
    const float* wr = ws + WS_N1T + d*256 + half*128;
    const float* si = shIn + half*128;
    float s = 0.f;
#pragma unroll 4
    for (int kk = 0; kk < 32; ++kk) {
      float4 wv = *(const float4*)(wr + kk*4);
      float4 iv = *(const float4*)(si + kk*4);
      s += wv.x*iv.x + wv.y*iv.y + wv.z*iv.z + wv.w*iv.w;
    }
    __syncthreads();   // pm reuse: msg reads done
    pm[t] = s;
  }
  __syncthreads();
  if (t < HID) shHid[t] = silu_f(nb1[t] + pm[t] + pm[t + 128]);
  __syncthreads();

  // ---- MLP layer 2 partials
  {
    const float* wr = ws + WS_N2T + d*128 + half*64;
    const float* si = shHid + half*64;
    float s = 0.f;
#pragma unroll 4
    for (int kk = 0; kk < 16; ++kk) {
      float4 wv = *(const float4*)(wr + kk*4);
      float4 iv = *(const float4*)(si + kk*4);
      s += wv.x*iv.x + wv.y*iv.y + wv.z*iv.z + wv.w*iv.w;
    }
    pm[t] = s;
  }
  __syncthreads();

  // ---- residual + LayerNorm (t < 128)
  float x = 0.f;
  if (t < HID) {
    x = shIn[t] + nb2[t] + pm[t] + pm[t + 128];
    float v1 = x, v2 = x*x;
#pragma unroll
    for (int off = 32; off > 0; off >>= 1) {
      v1 += __shfl_down(v1, off);
      v2 += __shfl_down(v2, off);
    }
    if (l == 0) { shred[w] = v1; shred[2 + w] = v2; }
  }
  __syncthreads();
  if (t < HID) {
    float mu  = (shred[0] + shred[1]) * (1.f/HID);
    float var = (shred[2] + shred[3]) * (1.f/HID) - mu*mu;
    float inv = 1.f / sqrtf(var + 1e-5f);
    out[node*HID + t] = (x - mu) * inv * lng[t] + lnb[t];
  }
}

// ---------------------------------------------------------------- launch
extern "C" void kernel_launch(void* const* d_in, const int* in_sizes, int n_in,
                              void* d_out, int out_size, void* d_ws, size_t ws_size,
                              hipStream_t stream) {
  (void)in_sizes; (void)n_in; (void)out_size; (void)ws_size;
  const float* h   = (const float*)d_in[0];
  const float* pos = (const float*)d_in[1];
  const float* vel = (const float*)d_in[2];
  const float* ew1 = (const float*)d_in[3];
  const float* eb1 = (const float*)d_in[4];
  const float* ew2 = (const float*)d_in[5];
  const float* eb2 = (const float*)d_in[6];
  const float* cw1 = (const float*)d_in[7];
  const float* cb1 = (const float*)d_in[8];
  const float* cw2 = (const float*)d_in[9];
  const float* cb2 = (const float*)d_in[10];
  const float* nw1 = (const float*)d_in[11];
  const float* nb1 = (const float*)d_in[12];
  const float* nw2 = (const float*)d_in[13];
  const float* nb2 = (const float*)d_in[14];
  const float* lng = (const float*)d_in[15];
  const float* lnb = (const float*)d_in[16];
  float* out = (float*)d_out;
  float* ws  = (float*)d_ws;
  unsigned short* wsU = (unsigned short*)d_ws;

  hipLaunchKernelGGL(k01_prep, dim3(593), dim3(256), 0, stream,
                     h, ew1, eb1, ew2, cw1, eb2, nw1, nw2, ws, wsU);
  hipLaunchKernelGGL(k3_edge, dim3(NNODE), dim3(256), 0, stream,
                     pos, vel, h, cb1, cw2, cb2, eb2,
                     nb1, nb2, lng, lnb, ws, out);
}

// Round 9
// 239.836 us; speedup vs baseline: 2.3397x; 1.0809x over previous
//
#include <hip/hip_runtime.h>
#include <math.h>

#define HID 128
#define NN 512
#define NNODE 1024
#define CUTR 10.0f

// ---- ws layout, float offsets
#define WS_A    0            // [1024][256] fp32  (A_i + bias + const-angular row)
#define WS_N1T  262144       // nw1^T fp32 [128][256]
#define WS_N2T  294912       // nw2^T fp32 [128][128]
#define WS_B12  393216       // [128] fp32  eb2 @ cw1
// ---- ws layout, ushort offsets
// BmT fragment-order bf16: [b][chunk16][g4][(col,hl)512][e4]
#define SBMT_OFF  786688                  // 262144 ushorts
#define SE2T_OFF  (SBMT_OFF + 262144)     // ew2^T bf16 [128][256]
// W12T fragment-order bf16: [s16][d128][hl2][e8]
#define SW12T_OFF (SE2T_OFF + 32768)      // 32768 ushorts
#define SW1G_OFF  (SW12T_OFF + 32768)     // W1g^T bf16 [256][16]

// ---- out layout (float offsets)
#define OUT_POS 131072
#define OUT_VEL 133120

typedef __attribute__((ext_vector_type(8)))  short short8;
typedef __attribute__((ext_vector_type(4)))  unsigned short ushort4v;
typedef __attribute__((ext_vector_type(8)))  __bf16 bf16x8;
typedef __attribute__((ext_vector_type(16))) float float16;

__device__ __forceinline__ float silu_f(float x) {
  return x * __builtin_amdgcn_rcpf(1.f + __expf(-x));
}
__device__ __forceinline__ short f2bf(float x) {
  return __builtin_bit_cast(short, (__bf16)x);   // native v_cvt (RNE)
}
__device__ __forceinline__ float bf2f(unsigned short u) {
  union { unsigned u; float f; } v; v.u = ((unsigned)u) << 16;
  return v.f;
}
__device__ __forceinline__ bf16x8 as_bf(short8 s) {
  return __builtin_bit_cast(bf16x8, s);
}
__device__ __forceinline__ float16 zero16() {
  float16 z;
#pragma unroll
  for (int r = 0; r < 16; ++r) z[r] = 0.f;
  return z;
}

// ---------------------------------------------------------------- K01
// Split-bf16 MFMA GEMM for A/Bm (r8, correct). 128 blocks x 4 waves;
// wave = one 32node x 32ucol tile; u<256 -> A (f32+bias store),
// u>=256 -> Bm (bf16, k3 fragment order). ucol = (ubase&255)+lo.
// blocks [128,593): weight prep (unchanged).
__global__ __launch_bounds__(256)
void k01_prep(const float* __restrict__ h, const float* __restrict__ ew1,
              const float* __restrict__ eb1, const float* __restrict__ ew2,
              const float* __restrict__ cw1, const float* __restrict__ eb2,
              const float* __restrict__ nw1, const float* __restrict__ nw2,
              float* __restrict__ ws, unsigned short* __restrict__ wsU) {
  int blk = blockIdx.x;
  int t = threadIdx.x;
  if (blk < 128) {
    const int w = t >> 6, l = t & 63, lo = l & 31, hl = l >> 5;
    const int tile  = blk * 4 + w;       // 0..511
    const int nbase = (tile >> 4) * 32;  // node tile base (32-aligned)
    const int ubase = (tile & 15) * 32;  // output-col tile base (0..511)
    const bool isA  = (ubase < 256);
    const int krow0 = isA ? 0 : 128;     // ew1 k-row base
    const int ucol  = (ubase & 255) + lo;  // ew1 COLUMN (0..255)

    float16 acc = zero16();
    const float* hrow = h + (nbase + lo) * HID;   // A-frag row = lane's node
#pragma unroll
    for (int s = 0; s < 8; ++s) {
      // A-frag: h[nbase+lo][16s + hl*8 + e], split hi/lo bf16
      const float* hp = hrow + 16 * s + hl * 8;
      float4 h0 = *(const float4*)(hp);
      float4 h1 = *(const float4*)(hp + 4);
      float av[8] = {h0.x, h0.y, h0.z, h0.w, h1.x, h1.y, h1.z, h1.w};
      short8 ah, al;
#pragma unroll
      for (int e = 0; e < 8; ++e) {
        ah[e] = f2bf(av[e]);
        al[e] = f2bf(av[e] - bf2f((unsigned short)ah[e]));
      }
      // B-frag: ew1[krow0 + 16s + hl*8 + e][ucol], split hi/lo bf16
      short8 bh, bl;
#pragma unroll
      for (int e = 0; e < 8; ++e) {
        float x = ew1[(krow0 + 16*s + hl*8 + e) * 256 + ucol];
        bh[e] = f2bf(x);
        bl[e] = f2bf(x - bf2f((unsigned short)bh[e]));
      }
      acc = __builtin_amdgcn_mfma_f32_32x32x16_bf16(as_bf(ah), as_bf(bh), acc, 0, 0, 0);
      acc = __builtin_amdgcn_mfma_f32_32x32x16_bf16(as_bf(ah), as_bf(bl), acc, 0, 0, 0);
      acc = __builtin_amdgcn_mfma_f32_32x32x16_bf16(as_bf(al), as_bf(bh), acc, 0, 0, 0);
    }

    // epilogue: C layout reg r -> row n = (r&3)+8*(r>>2)+4*hl, col = lo
    if (isA) {
      const float bias = eb1[ucol] + ew1[264*256 + ucol];
#pragma unroll
      for (int r = 0; r < 16; ++r) {
        const int n = (r & 3) + 8 * (r >> 2) + 4 * hl;
        ws[WS_A + (nbase + n) * 256 + ucol] = acc[r] + bias;
      }
    } else {
      const int bb = nbase >> 9;
      const int chunk = (nbase & 511) >> 5;
      // j-rel = n: e = r&3, g = r>>2, hlB = hl
      const int base = SBMT_OFF + bb*131072 + chunk*8192 + (ucol*2 + hl)*4;
#pragma unroll
      for (int r = 0; r < 16; ++r)
        wsU[base + (r >> 2) * 2048 + (r & 3)] = (unsigned short)f2bf(acc[r]);
    }
  } else {
    int idx = (blk - 128) * 256 + t;
    if (idx < 32768) {
      // W12T[d][cp] = sum_c ew2[cp][c] * cw1[c][d], fragment-order store
      int d = idx & 127, cp = idx >> 7;
      float s = 0.f;
#pragma unroll 4
      for (int c = 0; c < 128; ++c) s += ew2[cp*128 + c] * cw1[c*128 + d];
      int sg = cp >> 4, hlw = (cp >> 3) & 1, e = cp & 7;
      wsU[SW12T_OFF + sg*2048 + d*16 + hlw*8 + e] = (unsigned short)f2bf(s);
    } else if (idx < 65536) {
      int i2 = idx - 32768; int c = i2 >> 8, k = i2 & 255;
      wsU[SE2T_OFF + c*256 + k] = (unsigned short)f2bf(ew2[k*HID + c]);
    } else if (idx < 69632) {
      int i3 = idx - 65536; int c = i3 >> 4, f = i3 & 15;
      int row = (f < 8) ? (256 + f) : (257 + f);
      wsU[SW1G_OFF + c*16 + f] = (unsigned short)f2bf(ew1[row*256 + c]);
    } else if (idx < 69760) {
      int d = idx - 69632;
      float s = 0.f;
#pragma unroll 4
      for (int c = 0; c < 128; ++c) s += eb2[c] * cw1[c*128 + d];
      ws[WS_B12 + d] = s;
    } else if (idx < 102528) {
      int i4 = idx - 69760; int d = i4 >> 8, k = i4 & 255;
      ws[WS_N1T + d*256 + k] = nw1[k*HID + d];
    } else if (idx < 118912) {
      int i5 = idx - 102528; int d = i5 >> 7, k = i5 & 127;
      ws[WS_N2T + d*128 + k] = nw2[k*HID + d];
    }
  }
}

// ---------------------------------------------------------------- K3
// One block per (b,i); 4 waves. r8 structure (192us) + ROUND-9:
// __launch_bounds__(256,3) RETRY on the post-diet kernel.
// Rationale: r2's 3-wave attempt spilled on the FAT kernel (arch 116 +
// hp/bpermute/shfl state). After r3-r8 diet the kernel is arch 108 with
// fewer live chains; unified use is plausibly just over 170 only because
// no cap is declared. Instruction-count model says k3 is ~5x off the
// issue floor -> latency-exposed; +1 wave/SIMD is the only lever left.
// ADJUDICATION: if WRITE_SIZE balloons (scratch) or dur regresses ->
// revert to plain launch_bounds(256) permanently.
__global__ __launch_bounds__(256, 3)
void k3_edge(const float* __restrict__ pos, const float* __restrict__ vel,
             const float* __restrict__ h,
             const float* __restrict__ cb1, const float* __restrict__ cw2,
             const float* __restrict__ cb2, const float* __restrict__ eb2,
             const float* __restrict__ nb1, const float* __restrict__ nb2,
             const float* __restrict__ lng, const float* __restrict__ lnb,
             float* __restrict__ ws, float* __restrict__ out) {
  const short* wsS = (const short*)ws;
  const unsigned short* wsU = (const unsigned short*)ws;
  __shared__ __align__(16) short shH[2][32*256];  // bf16, xor-swizzled, double-buffered
  __shared__ float shsum[256];
  __shared__ float shred[12];
  __shared__ float4 shTbl[128];                   // {B12[d], cb1[d], cw2[d], 0}
  __shared__ __align__(16) float2 shPos[NN];      // batch positions
  __shared__ float shCut[32];                     // per-chunk cut broadcast

  const int t = threadIdx.x;
  const int w = t >> 6, l = t & 63, lo = l & 31, hl = l >> 5, hl4 = hl * 4;
  const int node = blockIdx.x;
  const int b = node >> 9;
  const int bN = b * NN;

  const bf16x8 wg0 = as_bf(*(const short8*)(wsS + SW1G_OFF + (64*w + lo)*16 + hl*8));
  const bf16x8 wg1 = as_bf(*(const short8*)(wsS + SW1G_OFF + (64*w + 32 + lo)*16 + hl*8));

  const float a0   = ws[WS_A + node*256 + 64*w + lo];
  const float a1   = ws[WS_A + node*256 + 64*w + 32 + lo];
  const float cb2c16 = cb2[0] * (16.f/128.f);
  const float pix  = pos[node*2], piy = pos[node*2+1];

  // stage pos (4KB) + fold table, once
  ((float4*)shPos)[t] = ((const float4*)(pos + 2*bN))[t];
  if (t < 128) shTbl[t] = make_float4(ws[WS_B12 + t], cb1[t], cw2[t], 0.f);
  __syncthreads();

  float hs0 = 0.f, hs1 = 0.f;    // hsum partials for cols 64w+lo, 64w+32+lo
  float cs = 0.f;                // sum_j cut_j (per-lane over own j's)
  float S = 0.f, SX = 0.f, SY = 0.f;
  float cutv, pjx, pjy;
  float cutv_n, pjx_n, pjy_n;

  auto phase1 = [&](int jbw, int bufsel) {
    const int jb = jbw & (NN - 1);
    const int chunk = jb >> 5;
    const float2 pj = shPos[jb + lo];
    pjx_n = pj.x; pjy_n = pj.y;
    const float dx = pix - pjx_n, dy = piy - pjy_n;
    const float d = sqrtf(dx*dx + dy*dy);
    cutv_n = (d < CUTR) ? 0.5f*(__cosf((float)M_PI*(1.f/CUTR)*d) + 1.f) : 0.f;
    if (jbw >= NN) cutv_n = 0.f;
    // publish cut for broadcast reads (all waves write identical values;
    // same-wave DS ordering guarantees our own reads see it)
    if (hl == 0) shCut[lo] = cutv_n;
    short8 gs;
    if (hl == 0) {
#pragma unroll
      for (int k = 0; k < 8; ++k) {
        float ctr = (CUTR * (float)k) / 7.0f;
        float tt = (d - ctr) * 0.8f;
        gs[k] = f2bf(__expf(-tt*tt));
      }
    } else {
      float invd = __builtin_amdgcn_rcpf(d + 1e-8f);
      float c1 = dx * invd, s1 = dy * invd;
      if (d == 0.f) { c1 = 1.f; s1 = 0.f; }
      float c2 = c1*c1 - s1*s1, s2 = 2.f*s1*c1;
      float c3 = c2*c1 - s2*s1, s3 = s2*c1 + c2*s1;
      float c4 = c3*c1 - s3*s1, s4 = s3*c1 + c3*s1;
      gs[0]=f2bf(c1); gs[1]=f2bf(c2); gs[2]=f2bf(c3); gs[3]=f2bf(c4);
      gs[4]=f2bf(s1); gs[5]=f2bf(s2); gs[6]=f2bf(s3); gs[7]=f2bf(s4);
    }
    const bf16x8 gf = as_bf(gs);
    short* shb = &shH[bufsel][0];
#pragma unroll
    for (int ct = 0; ct < 2; ++ct) {
      const int colg = 64*w + 32*ct + lo;
      const float av = ct ? a1 : a0;
      // fragment-order BmT: per-g ushort4v load is 64-lane contiguous
      const unsigned short* bt =
          wsU + SBMT_OFF + b*131072 + chunk*8192 + (colg*2 + hl)*4;
      float16 ci;
#pragma unroll
      for (int g = 0; g < 4; ++g) {
        ushort4v v4 = *(const ushort4v*)(bt + g*2048);
        ci[4*g+0] = bf2f(v4[0]) + av;
        ci[4*g+1] = bf2f(v4[1]) + av;
        ci[4*g+2] = bf2f(v4[2]) + av;
        ci[4*g+3] = bf2f(v4[3]) + av;
      }
      ci = __builtin_amdgcn_mfma_f32_32x32x16_bf16(gf, ct ? wg1 : wg0, ci, 0, 0, 0);
      const int ck = colg >> 3;
      float hacc = 0.f;
#pragma unroll
      for (int r = 0; r < 16; ++r) {
        int row = (r&3) + 8*(r>>2) + hl4;
        float sv = silu_f(ci[r]);
        hacc += shCut[row] * sv;    // broadcast ds_read (imm offset)
        shb[row*256 + (((ck ^ row) & 31) << 3) + (colg & 7)] = f2bf(sv);
      }
      if (ct) hs1 += hacc; else hs0 += hacc;
    }
  };

  // prologue: chunk 0 -> buf 0
  phase1(0, 0);
  cutv = cutv_n; pjx = pjx_n; pjy = pjy_n;
  __syncthreads();

  for (int k = 0; k < 16; ++k) {
    cs += cutv;

    // ---- coord GEMM, transposed: acc2 = W12T-frag * Hs-frag -> D[d][j]
    float16 acc2 = zero16();
    {
      const short* wp = wsS + SW12T_OFF + (32*w + lo)*16 + hl*8;
      const short* shb = &shH[k & 1][0];
#pragma unroll 4
      for (int s = 0; s < 16; ++s) {
        bf16x8 wv = as_bf(*(const short8*)(wp + s*2048));
        const int ck = 2*s + hl;
        bf16x8 af = as_bf(*(const short8*)(shb + lo*256 + (((ck ^ lo) & 31) << 3)));
        acc2 = __builtin_amdgcn_mfma_f32_32x32x16_bf16(wv, af, acc2, 0, 0, 0);
      }
    }

    // ---- phase1 for chunk k+1 -> other buffer (overlaps the GEMM)
    phase1((k + 1) * 32, (k + 1) & 1);

    // ---- epilogue (all lane-local): lane's own j; d indexed by r
    {
      float psum = 0.f;
#pragma unroll
      for (int r = 0; r < 16; ++r) {
        const float4 cst = shTbl[32*w + (r&3) + 8*(r>>2) + hl4];
        psum += silu_f(cutv * (acc2[r] + cst.x) + cst.y) * cst.z;
      }
      psum += cb2c16;
      S += psum;
      SX += psum * pjx;
      SY += psum * pjy;
    }

    cutv = cutv_n; pjx = pjx_n; pjy = pjy_n;
    __syncthreads();   // buf(k+1) writes complete; buf(k) reads complete
  }

  // ---- hsum: merge hl halves, stage to LDS
  hs0 += __shfl_xor(hs0, 32);
  hs1 += __shfl_xor(hs1, 32);
  if (hl == 0) {
    shsum[64*w + lo] = hs0;
    shsum[64*w + 32 + lo] = hs1;
  }

  // ---- cutsum: butterfly within 32 (identical across halves/waves)
  float cutsum = cs;
#pragma unroll
  for (int m = 1; m < 32; m <<= 1) cutsum += __shfl_xor(cutsum, m, 32);

  // ---- S/SX/SY wave reduce
#pragma unroll
  for (int off = 32; off > 0; off >>= 1) {
    S  += __shfl_xor(S, off);
    SX += __shfl_xor(SX, off);
    SY += __shfl_xor(SY, off);
  }
  if (l == 0) { shred[w] = S; shred[4 + w] = SX; shred[8 + w] = SY; }
  __syncthreads();

  // ================= fused node tail (all 256 threads) =================
  float* shIn  = (float*)&shH[0][0];    // 256 floats
  float* shHid = shIn + 256;            // 128 floats
  float* pm    = (float*)&shH[1][0];    // 256 float partials
  const int d  = t & 127, half = t >> 7;

  // ---- msg GEMV partials: pm[t] = sum over half of c' of hsum*ew2T
  {
    const short* er = wsS + SE2T_OFF + d*256 + half*128;
    const float* ss = shsum + half*128;
    float m = 0.f;
#pragma unroll 4
    for (int kk = 0; kk < 16; ++kk) {
      short8 v = *(const short8*)(er + kk*8);
      const float4 s0 = *(const float4*)(ss + kk*8);
      const float4 s1 = *(const float4*)(ss + kk*8 + 4);
      m += bf2f((unsigned short)v[0])*s0.x + bf2f((unsigned short)v[1])*s0.y
         + bf2f((unsigned short)v[2])*s0.z + bf2f((unsigned short)v[3])*s0.w
         + bf2f((unsigned short)v[4])*s1.x + bf2f((unsigned short)v[5])*s1.y
         + bf2f((unsigned short)v[6])*s1.z + bf2f((unsigned short)v[7])*s1.w;
    }
    pm[t] = m;
  }
  if (t == 0) {
    float St  = shred[0] + shred[1] + shred[2]  + shred[3];
    float SXt = shred[4] + shred[5] + shred[6]  + shred[7];
    float SYt = shred[8] + shred[9] + shred[10] + shred[11];
    float updx = pix*St - SXt, updy = piy*St - SYt;
    out[OUT_POS + node*2+0] = pix + updx;
    out[OUT_POS + node*2+1] = piy + updy;
    out[OUT_VEL + node*2+0] = vel[node*2+0] + 0.1f*updx;
    out[OUT_VEL + node*2+1] = vel[node*2+1] + 0.1f*updy;
  }
  __syncthreads();

  // ---- assemble node input: h | msg
  if (t < HID) {
    shIn[t]       = h[node*HID + t];
    shIn[HID + t] = pm[t] + pm[t + 128] + eb2[t] * cutsum;
  }
  __syncthreads();

  // ---- MLP layer 1: pm[t] = sum over half-k of shIn*nw1T (float4 loads)
  {
    const float* wr = ws + WS_N1T + d*256 + half*128;
    const float* si = shIn + half*128;
    float s = 0.f;
#pragma unroll 4
    for (int kk = 0; kk < 32; ++kk) {
      float4 wv = *(const float4*)(wr + kk*4);
      float4 iv = *(const float4*)(si + kk*4);
      s += wv.x*iv.x + wv.y*iv.y + wv.z*iv.z + wv.w*iv.w;
    }
    __syncthreads();   // pm reuse: msg reads done
    pm[t] = s;
  }
  __syncthreads();
  if (t < HID) shHid[t] = silu_f(nb1[t] + pm[t] + pm[t + 128]);
  __syncthreads();

  // ---- MLP layer 2 partials
  {
    const float* wr = ws + WS_N2T + d*128 + half*64;
    const float* si = shHid + half*64;
    float s = 0.f;
#pragma unroll 4
    for (int kk = 0; kk < 16; ++kk) {
      float4 wv = *(const float4*)(wr + kk*4);
      float4 iv = *(const float4*)(si + kk*4);
      s += wv.x*iv.x + wv.y*iv.y + wv.z*iv.z + wv.w*iv.w;
    }
    pm[t] = s;
  }
  __syncthreads();

  // ---- residual + LayerNorm (t < 128)
  float x = 0.f;
  if (t < HID) {
    x = shIn[t] + nb2[t] + pm[t] + pm[t + 128];
    float v1 = x, v2 = x*x;
#pragma unroll
    for (int off = 32; off > 0; off >>= 1) {
      v1 += __shfl_down(v1, off);
      v2 += __shfl_down(v2, off);
    }
    if (l == 0) { shred[w] = v1; shred[2 + w] = v2; }
  }
  __syncthreads();
  if (t < HID) {
    float mu  = (shred[0] + shred[1]) * (1.f/HID);
    float var = (shred[2] + shred[3]) * (1.f/HID) - mu*mu;
    float inv = 1.f / sqrtf(var + 1e-5f);
    out[node*HID + t] = (x - mu) * inv * lng[t] + lnb[t];
  }
}

// ---------------------------------------------------------------- launch
extern "C" void kernel_launch(void* const* d_in, const int* in_sizes, int n_in,
                              void* d_out, int out_size, void* d_ws, size_t ws_size,
                              hipStream_t stream) {
  (void)in_sizes; (void)n_in; (void)out_size; (void)ws_size;
  const float* h   = (const float*)d_in[0];
  const float* pos = (const float*)d_in[1];
  const float* vel = (const float*)d_in[2];
  const float* ew1 = (const float*)d_in[3];
  const float* eb1 = (const float*)d_in[4];
  const float* ew2 = (const float*)d_in[5];
  const float* eb2 = (const float*)d_in[6];
  const float* cw1 = (const float*)d_in[7];
  const float* cb1 = (const float*)d_in[8];
  const float* cw2 = (const float*)d_in[9];
  const float* cb2 = (const float*)d_in[10];
  const float* nw1 = (const float*)d_in[11];
  const float* nb1 = (const float*)d_in[12];
  const float* nw2 = (const float*)d_in[13];
  const float* nb2 = (const float*)d_in[14];
  const float* lng = (const float*)d_in[15];
  const float* lnb = (const float*)d_in[16];
  float* out = (float*)d_out;
  float* ws  = (float*)d_ws;
  unsigned short* wsU = (unsigned short*)d_ws;

  hipLaunchKernelGGL(k01_prep, dim3(593), dim3(256), 0, stream,
                     h, ew1, eb1, ew2, cw1, eb2, nw1, nw2, ws, wsU);
  hipLaunchKernelGGL(k3_edge, dim3(NNODE), dim3(256), 0, stream,
                     pos, vel, h, cb1, cw2, cb2, eb2,
                     nb1, nb2, lng, lnb, ws, out);
}